// Round 11
// baseline (378.604 us; speedup 1.0000x reference)
//
#include <hip/hip_runtime.h>

typedef unsigned short ushort_t;
typedef unsigned int   uint32;
typedef __attribute__((ext_vector_type(8))) short short8;
typedef __attribute__((ext_vector_type(4))) float f32x4;

#define DEV __device__ __forceinline__

// ---- problem dims ----
#define KC 16
#define DZ 64
#define DT 1024
#define NT 2048
#define NI 4096
#define KD 1024   // K*DZ

// ---- output element offsets (return-order concat, float32) ----
#define O_MU_ZT   0
#define O_LV_ZT   131072
#define O_MU_P    262144
#define O_LV_P    263168
#define O_CATES   264192
#define O_MU_ZI   296960
#define O_LV_ZI   4491264
#define O_ZI      8685568
#define O_APRED   12879872
#define O_MU_Y    21268480
#define O_LV_Y    21272576
#define O_AREC    21276672

// ---- workspace layout (floats) ----
#define WSF_ZT   0          // [NT*DZ]
#define WSF_C    131072     // [NT*KC]   c_sample (double softmax)
#define WSF_CT   163840     // [KC*NT]   c_sample transposed
#define WSF_AZT  196608     // [NI*DZ]
#define WSF_END  458752
// ushort region starts at WSF_END floats
#define WSU_ZTB  0          // [NT*DZ]   zt bf16
#define WSU_BC   131072     // [2048*NT] Bc bf16
#define WSU_ZIB  4325376    // [KC*NI*DZ] zi bf16
#define WSU_INSB 8519680    // [NI*NT]   ins bf16
#define WSU_ZHT  16908288   // [DZ*NT]   zt^T hi bf16
#define WSU_ZLT  17039360   // [DZ*NT]   zt^T lo bf16
#define WSU_WBH  17170432   // [128*DT]  [Wmu_zt;Wlv_zt] hi bf16
#define WSU_WBL  17301504   // [128*DT]  [Wmu_zt;Wlv_zt] lo bf16
#define WSU_END  17432576   // end of ushort region; W1T floats start here

DEV ushort_t f2b(float f){
  uint32 u = __float_as_uint(f);
  u += 0x7fffu + ((u >> 16) & 1u);   // RNE
  return (ushort_t)(u >> 16);
}
DEV uint32 pk(float lo, float hi){  // truncating bf16 pack (2 VALU ops)
  return (__float_as_uint(hi) & 0xffff0000u) | (__float_as_uint(lo) >> 16);
}
DEV float wred64(float v){
#pragma unroll
  for (int m = 32; m; m >>= 1) v += __shfl_xor(v, m, 64);
  return v;
}
DEV float fastrcp(float x){ return __builtin_amdgcn_rcpf(x); }  // v_rcp_f32, ~1ulp
// async global->LDS, 16B per lane (dest = wave-uniform base + lane*16)
DEV void gl2lds16(ushort_t* l, const ushort_t* g){
  __builtin_amdgcn_global_load_lds(
      (const __attribute__((address_space(1))) unsigned int*)g,
      (__attribute__((address_space(3))) unsigned int*)l, 16, 0, 0);
}

// ---------------- P0: dep-free prep — insb bf16, Wy1^T, W_zt hi/lo split, copies ----------------
__global__ __launch_bounds__(256) void k_prep0(
    const float* __restrict__ ins, const float* __restrict__ Wy1,
    const float* __restrict__ Wmzt, const float* __restrict__ Wlzt,
    const float* __restrict__ mu_p, const float* __restrict__ lv_p,
    ushort_t* __restrict__ insb, float* __restrict__ w1T,
    ushort_t* __restrict__ wbh, ushort_t* __restrict__ wbl,
    float* __restrict__ out)
{
  const int bx = blockIdx.x, tid = threadIdx.x;
  if (bx < 2048){
    const int g = bx * 256 + tid;            // 0..524287
    const int base = g * 16;                 // NI*NT = 8388608
    const float4* src = (const float4*)(ins + base);
    float4 z0 = src[0], z1 = src[1], z2 = src[2], z3 = src[3];
    ushort_t v[16];
    v[0]=f2b(z0.x); v[1]=f2b(z0.y); v[2]=f2b(z0.z); v[3]=f2b(z0.w);
    v[4]=f2b(z1.x); v[5]=f2b(z1.y); v[6]=f2b(z1.z); v[7]=f2b(z1.w);
    v[8]=f2b(z2.x); v[9]=f2b(z2.y); v[10]=f2b(z2.z); v[11]=f2b(z2.w);
    v[12]=f2b(z3.x); v[13]=f2b(z3.y); v[14]=f2b(z3.z); v[15]=f2b(z3.w);
    *(uint4*)(insb + base) = *(uint4*)&v[0];
    *(uint4*)(insb + base + 8) = *(uint4*)&v[8];
  } else if (bx < 2064){
    // Wy1^T: block handles 64 j-rows x 64 d -> w1T[d][j] (LDS transpose)
    __shared__ float wsh[64 * 65];
    const int j0 = (bx - 2048) * 64;
#pragma unroll
    for (int jj = 0; jj < 16; ++jj){
      const int idx = jj * 256 + tid;
      const int r = idx >> 6, d = idx & 63;
      wsh[r * 65 + d] = Wy1[(size_t)(j0 + r) * DZ + d];
    }
    __syncthreads();
    const int d = tid >> 2, q = tid & 3;
    float v[16];
#pragma unroll
    for (int i = 0; i < 16; ++i) v[i] = wsh[(q*16 + i)*65 + d];
#pragma unroll
    for (int i = 0; i < 4; ++i){
      float4 o; o.x = v[i*4]; o.y = v[i*4+1]; o.z = v[i*4+2]; o.w = v[i*4+3];
      *(float4*)&w1T[(size_t)d * KD + j0 + q*16 + i*4] = o;
    }
  } else if (bx < 2128){
    // [Wmu_zt;Wlv_zt] hi/lo bf16 split: rows 0..63 = mu, 64..127 = lv (no transpose)
    const int idx = (bx - 2064) * 2048 + tid * 8;   // 0..131071
    const int row = idx >> 10, k = idx & 1023;
    const float* src = (row < 64 ? Wmzt + (size_t)row * DT
                                 : Wlzt + (size_t)(row - 64) * DT) + k;
    float4 a0 = *(const float4*)src, a1 = *(const float4*)(src + 4);
    float f[8] = {a0.x, a0.y, a0.z, a0.w, a1.x, a1.y, a1.z, a1.w};
    ushort_t vh[8], vl[8];
#pragma unroll
    for (int i = 0; i < 8; ++i){
      const uint32 u = __float_as_uint(f[i]);
      vh[i] = (ushort_t)(u >> 16);
      const float hf = __uint_as_float(u & 0xffff0000u);
      vl[i] = (ushort_t)(__float_as_uint(f[i] - hf) >> 16);
    }
    *(uint4*)(wbh + (size_t)row * DT + k) = *(uint4*)vh;
    *(uint4*)(wbl + (size_t)row * DT + k) = *(uint4*)vl;
  } else {
    const int i = (bx - 2128) * 256 + tid;   // 0..1023
    out[O_MU_P + i] = mu_p[i];
    out[O_LV_P + i] = lv_p[i];
  }
}

// ---------------- A: encode_t — compensated bf16 MFMA GEMM, split-K 8 waves ----------------
__global__ __launch_bounds__(512) void k_encode_t(
    const float* __restrict__ treat, const ushort_t* __restrict__ wbh,
    const ushort_t* __restrict__ wbl, const float* __restrict__ bmu,
    const float* __restrict__ blv, float* __restrict__ out,
    float* __restrict__ ws_zt)
{
  __shared__ float red[16 * 128];
  const int tid = threadIdx.x;
  const int n0 = blockIdx.x * 16;
  const int w = tid >> 6, lane = tid & 63;
  const int kh = w >> 2, wd = w & 3;       // kh: K-half; wd: col-quadrant
  const int l16 = lane & 15, quad = lane >> 4;
  const float* aRow = treat + (size_t)(n0 + l16) * DT + kh * 512 + quad * 8;
  const int colA = wd * 16 + l16;          // mu col 0..63; lv col = colA+64
  const ushort_t* bhA = wbh + (size_t)colA * DT + kh * 512 + quad * 8;
  const ushort_t* blA = wbl + (size_t)colA * DT + kh * 512 + quad * 8;
  const ushort_t* bhB = wbh + (size_t)(colA + 64) * DT + kh * 512 + quad * 8;
  const ushort_t* blB = wbl + (size_t)(colA + 64) * DT + kh * 512 + quad * 8;
  f32x4 accA = {}, accB = {};
#pragma unroll 4
  for (int kt = 0; kt < 16; ++kt){
    const int ko = kt * 32;
    float4 a0 = *(const float4*)(aRow + ko);
    float4 a1 = *(const float4*)(aRow + ko + 4);
    uint32 u0 = __float_as_uint(a0.x), u1 = __float_as_uint(a0.y);
    uint32 u2 = __float_as_uint(a0.z), u3 = __float_as_uint(a0.w);
    uint32 u4 = __float_as_uint(a1.x), u5 = __float_as_uint(a1.y);
    uint32 u6 = __float_as_uint(a1.z), u7 = __float_as_uint(a1.w);
    uint4 H, L;
    H.x = (u1 & 0xffff0000u) | (u0 >> 16);
    H.y = (u3 & 0xffff0000u) | (u2 >> 16);
    H.z = (u5 & 0xffff0000u) | (u4 >> 16);
    H.w = (u7 & 0xffff0000u) | (u6 >> 16);
    float l0 = a0.x - __uint_as_float(u0 & 0xffff0000u);
    float l1 = a0.y - __uint_as_float(u1 & 0xffff0000u);
    float l2 = a0.z - __uint_as_float(u2 & 0xffff0000u);
    float l3 = a0.w - __uint_as_float(u3 & 0xffff0000u);
    float l4 = a1.x - __uint_as_float(u4 & 0xffff0000u);
    float l5 = a1.y - __uint_as_float(u5 & 0xffff0000u);
    float l6 = a1.z - __uint_as_float(u6 & 0xffff0000u);
    float l7 = a1.w - __uint_as_float(u7 & 0xffff0000u);
    L.x = pk(l0, l1); L.y = pk(l2, l3); L.z = pk(l4, l5); L.w = pk(l6, l7);
    short8 ah = *(short8*)&H, al = *(short8*)&L;
    short8 hA = *(const short8*)(bhA + ko), lA = *(const short8*)(blA + ko);
    short8 hB = *(const short8*)(bhB + ko), lB = *(const short8*)(blB + ko);
    accA = __builtin_amdgcn_mfma_f32_16x16x32_bf16(ah, hA, accA, 0, 0, 0);
    accA = __builtin_amdgcn_mfma_f32_16x16x32_bf16(al, hA, accA, 0, 0, 0);
    accA = __builtin_amdgcn_mfma_f32_16x16x32_bf16(ah, lA, accA, 0, 0, 0);
    accB = __builtin_amdgcn_mfma_f32_16x16x32_bf16(ah, hB, accB, 0, 0, 0);
    accB = __builtin_amdgcn_mfma_f32_16x16x32_bf16(al, hB, accB, 0, 0, 0);
    accB = __builtin_amdgcn_mfma_f32_16x16x32_bf16(ah, lB, accB, 0, 0, 0);
  }
  if (kh == 1){
#pragma unroll
    for (int reg = 0; reg < 4; ++reg){
      red[(quad*4 + reg)*128 + colA]      = accA[reg];
      red[(quad*4 + reg)*128 + colA + 64] = accB[reg];
    }
  }
  __syncthreads();
  if (kh == 0){
    const float bA = bmu[colA], bB = blv[colA];
#pragma unroll
    for (int reg = 0; reg < 4; ++reg){
      const int row = n0 + quad*4 + reg;
      const float vA = accA[reg] + red[(quad*4 + reg)*128 + colA] + bA;
      const float vB = accB[reg] + red[(quad*4 + reg)*128 + colA + 64] + bB;
      out[O_MU_ZT + row*DZ + colA] = vA;
      ws_zt[row*DZ + colA] = vA;
      out[O_LV_ZT + row*DZ + colA] = vB;
    }
  }
}

// ---------------- B: qc -> cates -> c_sample ----------------
__global__ __launch_bounds__(256) void k_qc(
    const float* __restrict__ mu_p, const float* __restrict__ ws_zt,
    float* __restrict__ out, float* __restrict__ ws_c, float* __restrict__ ws_cT)
{
  const int tid = threadIdx.x, lane = tid & 63;
  const int row = blockIdx.x * 4 + (tid >> 6);
  const float z = ws_zt[row * DZ + lane];
  const float nz = sqrtf(wred64(z * z));
  float myqc = 0.f;
#pragma unroll
  for (int k = 0; k < KC; ++k){
    float cv  = 5.f * mu_p[k * DZ + lane];
    float dot = wred64(z * cv);
    float nc2 = wred64(cv * cv);
    float qc  = 10.f * dot / fmaxf(nz * sqrtf(nc2), 1e-6f);
    if (lane == k) myqc = qc;
  }
  float mx = myqc;
#pragma unroll
  for (int m = 8; m; m >>= 1) mx = fmaxf(mx, __shfl_xor(mx, m, 16));
  float e = __expf(myqc - mx);
  float s = e;
#pragma unroll
  for (int m = 8; m; m >>= 1) s += __shfl_xor(s, m, 16);
  float cates = e / s;
  float mx2 = cates;
#pragma unroll
  for (int m = 8; m; m >>= 1) mx2 = fmaxf(mx2, __shfl_xor(mx2, m, 16));
  float e2 = __expf(cates - mx2);
  float s2 = e2;
#pragma unroll
  for (int m = 8; m; m >>= 1) s2 += __shfl_xor(s2, m, 16);
  float c2 = e2 / s2;
  if (lane < KC){
    out[O_CATES + row * KC + lane] = cates;
    ws_c[row * KC + lane] = c2;
    ws_cT[lane * NT + row] = c2;
  }
}

// ---------------- P1: zt-dependent prep — Bc bf16, ztb bf16, ztT hi/lo ----------------
__global__ __launch_bounds__(256) void k_prep1(
    const float* __restrict__ Wmu, const float* __restrict__ Wlv,
    const float* __restrict__ cT, const float* __restrict__ zt,
    ushort_t* __restrict__ Bc, ushort_t* __restrict__ ztb,
    ushort_t* __restrict__ zhT, ushort_t* __restrict__ zlT)
{
  const int bx = blockIdx.x, tid = threadIdx.x;
  if (bx < 2048){
    const int j = bx;
    const bool isMu = j < KD;
    const int kk = (j & (KD-1)) >> 6, d = j & 63;
    const float* W = (isMu ? Wmu : Wlv) + (size_t)d * NT;
    const float* c = cT + (size_t)kk * NT;
    const int t = tid * 8;
    float4 w0 = *(const float4*)(W + t), w1 = *(const float4*)(W + t + 4);
    float4 c0 = *(const float4*)(c + t), c1 = *(const float4*)(c + t + 4);
    ushort_t v[8];
    v[0]=f2b(w0.x*c0.x); v[1]=f2b(w0.y*c0.y); v[2]=f2b(w0.z*c0.z); v[3]=f2b(w0.w*c0.w);
    v[4]=f2b(w1.x*c1.x); v[5]=f2b(w1.y*c1.y); v[6]=f2b(w1.z*c1.z); v[7]=f2b(w1.w*c1.w);
    *(uint4*)(Bc + (size_t)j * NT + t) = *(uint4*)v;
  } else if (bx < 2080){
    const int g = (bx - 2048) * 256 + tid;   // 0..8191
    const int base = g * 16;                 // NT*DZ = 131072
    const float4* src = (const float4*)(zt + base);
    float4 z0 = src[0], z1 = src[1], z2 = src[2], z3 = src[3];
    ushort_t v[16];
    v[0]=f2b(z0.x); v[1]=f2b(z0.y); v[2]=f2b(z0.z); v[3]=f2b(z0.w);
    v[4]=f2b(z1.x); v[5]=f2b(z1.y); v[6]=f2b(z1.z); v[7]=f2b(z1.w);
    v[8]=f2b(z2.x); v[9]=f2b(z2.y); v[10]=f2b(z2.z); v[11]=f2b(z2.w);
    v[12]=f2b(z3.x); v[13]=f2b(z3.y); v[14]=f2b(z3.z); v[15]=f2b(z3.w);
    *(uint4*)(ztb + base) = *(uint4*)&v[0];
    *(uint4*)(ztb + base + 8) = *(uint4*)&v[8];
  } else {
    // zt^T hi/lo split: block handles 64 t-rows x 64 d (LDS transpose)
    __shared__ float zsh[64 * 65];
    const int t0 = (bx - 2080) * 64;
#pragma unroll
    for (int jj = 0; jj < 16; ++jj){
      const int idx = jj * 256 + tid;
      const int t = idx >> 6, d = idx & 63;
      zsh[t * 65 + d] = zt[(size_t)(t0 + t) * DZ + d];
    }
    __syncthreads();
    const int d = tid >> 2, tq = tid & 3;
    ushort_t vh[16], vl[16];
#pragma unroll
    for (int i = 0; i < 16; ++i){
      const float f = zsh[(tq * 16 + i) * 65 + d];
      const uint32 u = __float_as_uint(f);
      vh[i] = (ushort_t)(u >> 16);                       // trunc hi
      const float hf = __uint_as_float(u & 0xffff0000u);
      vl[i] = (ushort_t)(__float_as_uint(f - hf) >> 16); // trunc lo
    }
    *(uint4*)(zhT + (size_t)d * NT + t0 + tq * 16)     = *(uint4*)&vh[0];
    *(uint4*)(zhT + (size_t)d * NT + t0 + tq * 16 + 8) = *(uint4*)&vh[8];
    *(uint4*)(zlT + (size_t)d * NT + t0 + tq * 16)     = *(uint4*)&vl[0];
    *(uint4*)(zlT + (size_t)d * NT + t0 + tq * 16 + 8) = *(uint4*)&vl[8];
  }
}

// ---------------- C: encode_i — MFMA GEMM, 128x64 tile (was 128x128: grid 512 =
//   2 blocks/CU, grid-limited occupancy 17%, barrier drain unhidden). 1024 blocks
//   = 4/CU, LDS 24KB. Single-buffer, global_load_lds w16, T2 XOR-swizzle. ----------
__global__ __launch_bounds__(256) void k_encode_i(
    const ushort_t* __restrict__ insb, const ushort_t* __restrict__ Bc,
    const float* __restrict__ bmu, const float* __restrict__ blv,
    float* __restrict__ out, ushort_t* __restrict__ zib)
{
  __shared__ ushort_t As[128*64];   // [row][k], 16B-chunk XOR-swizzled by (row&7)
  __shared__ ushort_t Bs[64*64];
  const int tid = threadIdx.x;
  const int j0 = blockIdx.x * 64, n0 = blockIdx.y * 128;
  const int w = tid >> 6, lane = tid & 63;
  const int wm = w & 1, wn = w >> 1;
  const int l16 = lane & 15, quad = lane >> 4;

  const int srow = tid >> 3, schunk = (tid & 7) ^ (srow & 7);
  const ushort_t* aSrc = insb + (size_t)(n0 + srow) * NT + schunk * 8;
  const ushort_t* bSrc = Bc  + (size_t)(j0 + srow) * NT + schunk * 8;
  ushort_t* aDst = &As[tid * 8];
  ushort_t* bDst = &Bs[tid * 8];

  f32x4 acc[4][2] = {};

  for (int kt = 0; kt < NT/64; ++kt){
    const ushort_t* ak = aSrc + kt * 64;
    const ushort_t* bk = bSrc + kt * 64;
#pragma unroll
    for (int i = 0; i < 4; ++i)          // A: 128 rows, 32-row steps (row&7 invariant)
      gl2lds16(aDst + i * 2048, ak + (size_t)i * 32 * NT);
#pragma unroll
    for (int i = 0; i < 2; ++i)          // B: 64 rows
      gl2lds16(bDst + i * 2048, bk + (size_t)i * 32 * NT);
    __syncthreads();
#pragma unroll
    for (int ks = 0; ks < 2; ++ks){
      const int rsw = ((ks*4 + quad) ^ (l16 & 7)) * 8;
      short8 af[4], bf[2];
#pragma unroll
      for (int mf = 0; mf < 4; ++mf)
        af[mf] = *(const short8*)&As[(wm*64 + mf*16 + l16)*64 + rsw];
#pragma unroll
      for (int nf = 0; nf < 2; ++nf)
        bf[nf] = *(const short8*)&Bs[(wn*32 + nf*16 + l16)*64 + rsw];
#pragma unroll
      for (int mf = 0; mf < 4; ++mf)
#pragma unroll
        for (int nf = 0; nf < 2; ++nf)
          acc[mf][nf] = __builtin_amdgcn_mfma_f32_16x16x32_bf16(af[mf], bf[nf], acc[mf][nf], 0, 0, 0);
    }
    __syncthreads();
  }

  const int colW = j0 + wn * 32;          // 32-aligned within a 64-col d-group
  const bool isMu = colW < KD;
  const int kk = (colW & (KD - 1)) >> 6;
  const int dBase = colW & 63;            // 0 or 32
  const float* bias = isMu ? bmu : blv;
  const size_t zbase = (size_t)kk * (NI * DZ);
#pragma unroll
  for (int mf = 0; mf < 4; ++mf){
    const int r = n0 + wm*64 + mf*16 + quad*4;
#pragma unroll
    for (int nf = 0; nf < 2; ++nf){
      const int d = dBase + nf*16 + l16;
      const float bv = bias[d];
#pragma unroll
      for (int reg = 0; reg < 4; ++reg){
        float v = acc[mf][nf][reg] + bv;
        size_t idx = zbase + (size_t)(r + reg)*DZ + d;
        if (isMu){
          out[O_MU_ZI + idx] = v;
          out[O_ZI + idx] = v;
          zib[idx] = f2b(v);
        } else {
          out[O_LV_ZI + idx] = v;
        }
      }
    }
  }
}

// ---------------- D: decoder — per-k MFMA, 128x64 tile, XOR-swizzled LDS,
//   k-invariant Zt fragments hoisted to registers, rcp sigmoid ----------------
__global__ __launch_bounds__(256) void k_decoder(
    const ushort_t* __restrict__ ztb, const ushort_t* __restrict__ zib,
    const float* __restrict__ ws_c, float* __restrict__ out)
{
  __shared__ ushort_t Zt[64*64];    // [t][64d], 16B-chunk XOR-swizzled by (row&7)
  __shared__ ushort_t Zi[128*64];   // [n][64d], 16B-chunk XOR-swizzled by (row&7)
  __shared__ float ct[64*17];       // c_sample, padded
  const int tid = threadIdx.x;
  const int t0 = blockIdx.x * 64, n0 = blockIdx.y * 128;
  const int w = tid >> 6, lane = tid & 63;
  const int wm = w & 1, wn = w >> 1;
  const int l16 = lane & 15, quad = lane >> 4;
  const int zr = tid >> 2, zq = tid & 3;   // Zt: 4 threads/row, 16 shorts each
  const int ir = tid >> 1, ih = tid & 1;   // Zi: 2 threads/row, 32 shorts each
  {
    const uint4* src = (const uint4*)(ztb + (size_t)(t0 + zr)*DZ + zq*16);
    uint4 z0 = src[0], z1 = src[1];
    ushort_t* dst = &Zt[zr*64];
    *(uint4*)&dst[((zq*2 + 0) ^ (zr & 7)) * 8] = z0;
    *(uint4*)&dst[((zq*2 + 1) ^ (zr & 7)) * 8] = z1;
  }
  for (int i = tid; i < 64*16; i += 256){
    int t = i >> 4, k = i & 15;
    ct[t*17 + k] = ws_c[(size_t)(t0 + t)*KC + k];
  }
  __syncthreads();   // Zt + ct visible
  short8 bfh[2][2];
#pragma unroll
  for (int ks = 0; ks < 2; ++ks){
    const int rsw = ((ks*4 + quad) ^ (l16 & 7)) * 8;
#pragma unroll
    for (int nf = 0; nf < 2; ++nf)
      bfh[ks][nf] = *(const short8*)&Zt[(wn*32 + nf*16 + l16)*64 + rsw];
  }
  const ushort_t* iG = zib + (size_t)(n0 + ir)*DZ + ih*32;
  ushort_t* isw = &Zi[ir*64];
  const int sw0 = ((ih*4 + 0) ^ (ir & 7)) * 8;
  const int sw1 = ((ih*4 + 1) ^ (ir & 7)) * 8;
  const int sw2 = ((ih*4 + 2) ^ (ir & 7)) * 8;
  const int sw3 = ((ih*4 + 3) ^ (ir & 7)) * 8;
  uint4 Zr0, Zr1, Zr2, Zr3;
  {
    const uint4* zp = (const uint4*)iG;
    Zr0 = zp[0]; Zr1 = zp[1]; Zr2 = zp[2]; Zr3 = zp[3];
  }
  f32x4 accum[4][2] = {};
  for (int k = 0; k < KC; ++k){
    __syncthreads();
    *(uint4*)&isw[sw0] = Zr0; *(uint4*)&isw[sw1] = Zr1;
    *(uint4*)&isw[sw2] = Zr2; *(uint4*)&isw[sw3] = Zr3;
    __syncthreads();
    if (k < KC - 1){
      const uint4* zp = (const uint4*)(iG + (size_t)(k+1)*(NI*DZ));
      Zr0 = zp[0]; Zr1 = zp[1]; Zr2 = zp[2]; Zr3 = zp[3];
    }
    f32x4 s[4][2] = {};
#pragma unroll
    for (int ks = 0; ks < 2; ++ks){
      const int rsw = ((ks*4 + quad) ^ (l16 & 7)) * 8;
      short8 af[4];
#pragma unroll
      for (int mf = 0; mf < 4; ++mf)
        af[mf] = *(const short8*)&Zi[(wm*64 + mf*16 + l16)*64 + rsw];
#pragma unroll
      for (int mf = 0; mf < 4; ++mf)
#pragma unroll
        for (int nf = 0; nf < 2; ++nf)
          s[mf][nf] = __builtin_amdgcn_mfma_f32_16x16x32_bf16(af[mf], bfh[ks][nf], s[mf][nf], 0, 0, 0);
    }
#pragma unroll
    for (int nf = 0; nf < 2; ++nf){
      const float cv = ct[(wn*32 + nf*16 + l16)*17 + k];
#pragma unroll
      for (int mf = 0; mf < 4; ++mf)
#pragma unroll
        for (int reg = 0; reg < 4; ++reg)
          accum[mf][nf][reg] += cv * fastrcp(1.f + __expf(-s[mf][nf][reg]));
    }
  }
#pragma unroll
  for (int mf = 0; mf < 4; ++mf){
    const int r = n0 + wm*64 + mf*16 + quad*4;
#pragma unroll
    for (int nf = 0; nf < 2; ++nf){
      const int col = t0 + wn*32 + nf*16 + l16;
#pragma unroll
      for (int reg = 0; reg < 4; ++reg)
        out[O_APRED + (size_t)(r + reg)*NT + col] = accum[mf][nf][reg];
    }
  }
}

// ---------------- E: a_reconst — 8 rows/block, 512 threads (2 j-rows/thread) ----------------
__global__ __launch_bounds__(512) void k_arec(
    const float* __restrict__ ws_zt, const float* __restrict__ W,
    const float* __restrict__ bias, float* __restrict__ out)
{
  __shared__ float zsh[8 * DZ];
  const int n0 = blockIdx.x * 8, tid = threadIdx.x;
  if (tid < 128)
    ((float4*)zsh)[tid] = ((const float4*)(ws_zt + (size_t)n0 * DZ))[tid];
  __syncthreads();
#pragma unroll
  for (int jo = 0; jo < 2; ++jo){
    const int j = jo*512 + tid;
    const float4* w4 = (const float4*)(W + (size_t)j * DZ);
    const float b = bias[j];
    float acc[8];
#pragma unroll
    for (int r = 0; r < 8; ++r) acc[r] = b;
#pragma unroll
    for (int i = 0; i < 16; ++i){
      float4 wv = w4[i];
#pragma unroll
      for (int r = 0; r < 8; ++r){
        const float* z = &zsh[r*DZ + i*4];
        acc[r] += wv.x*z[0] + wv.y*z[1] + wv.z*z[2] + wv.w*z[3];
      }
    }
#pragma unroll
    for (int r = 0; r < 8; ++r)
      out[O_AREC + (size_t)(n0 + r)*DT + j] = fastrcp(1.f + __expf(-acc[r]));
  }
}

// ---------------- F1: a_zt = ins @ zt — compensated bf16 MFMA, split-K 8 waves ----
__global__ __launch_bounds__(512) void k_azt(
    const float* __restrict__ ins, const ushort_t* __restrict__ zhT,
    const ushort_t* __restrict__ zlT, float* __restrict__ azt)
{
  __shared__ float red[16*64];
  const int tid = threadIdx.x;
  const int n0 = blockIdx.x * 16;
  const int w = tid >> 6, lane = tid & 63;
  const int kh = w >> 2, wd = w & 3;       // kh: K-half; wd: d-quadrant
  const int l16 = lane & 15, quad = lane >> 4;
  const float* aRow = ins + (size_t)(n0 + l16) * NT + kh * 1024 + quad * 8;
  const ushort_t* bh = zhT + (size_t)(wd * 16 + l16) * NT + kh * 1024 + quad * 8;
  const ushort_t* bl = zlT + (size_t)(wd * 16 + l16) * NT + kh * 1024 + quad * 8;
  f32x4 acc = {};
#pragma unroll 4
  for (int kt = 0; kt < 16; ++kt){
#pragma unroll
    for (int ks = 0; ks < 2; ++ks){
      const int ko = kt * 64 + ks * 32;
      float4 a0 = *(const float4*)(aRow + ko);
      float4 a1 = *(const float4*)(aRow + ko + 4);
      uint32 u0 = __float_as_uint(a0.x), u1 = __float_as_uint(a0.y);
      uint32 u2 = __float_as_uint(a0.z), u3 = __float_as_uint(a0.w);
      uint32 u4 = __float_as_uint(a1.x), u5 = __float_as_uint(a1.y);
      uint32 u6 = __float_as_uint(a1.z), u7 = __float_as_uint(a1.w);
      uint4 H, L;
      H.x = (u1 & 0xffff0000u) | (u0 >> 16);
      H.y = (u3 & 0xffff0000u) | (u2 >> 16);
      H.z = (u5 & 0xffff0000u) | (u4 >> 16);
      H.w = (u7 & 0xffff0000u) | (u6 >> 16);
      float l0 = a0.x - __uint_as_float(u0 & 0xffff0000u);
      float l1 = a0.y - __uint_as_float(u1 & 0xffff0000u);
      float l2 = a0.z - __uint_as_float(u2 & 0xffff0000u);
      float l3 = a0.w - __uint_as_float(u3 & 0xffff0000u);
      float l4 = a1.x - __uint_as_float(u4 & 0xffff0000u);
      float l5 = a1.y - __uint_as_float(u5 & 0xffff0000u);
      float l6 = a1.z - __uint_as_float(u6 & 0xffff0000u);
      float l7 = a1.w - __uint_as_float(u7 & 0xffff0000u);
      L.x = pk(l0, l1); L.y = pk(l2, l3); L.z = pk(l4, l5); L.w = pk(l6, l7);
      short8 ah = *(short8*)&H, al = *(short8*)&L;
      short8 bh8 = *(const short8*)(bh + ko);
      short8 bl8 = *(const short8*)(bl + ko);
      acc = __builtin_amdgcn_mfma_f32_16x16x32_bf16(ah, bh8, acc, 0, 0, 0);
      acc = __builtin_amdgcn_mfma_f32_16x16x32_bf16(al, bh8, acc, 0, 0, 0);
      acc = __builtin_amdgcn_mfma_f32_16x16x32_bf16(ah, bl8, acc, 0, 0, 0);
    }
  }
  const int col = wd * 16 + l16;
  if (kh == 1){
#pragma unroll
    for (int reg = 0; reg < 4; ++reg)
      red[(quad*4 + reg)*64 + col] = acc[reg];
  }
  __syncthreads();
  if (kh == 0){
#pragma unroll
    for (int reg = 0; reg < 4; ++reg)
      azt[(size_t)(n0 + quad*4 + reg) * DZ + col] = acc[reg] + red[(quad*4 + reg)*64 + col];
  }
}

// ---------------- F2: mu_y / logvar_y — coalesced via Wy1^T, 2 j/thread, fp32 ----------------
__global__ __launch_bounds__(512) void k_muy(
    const float* __restrict__ azt, const float* __restrict__ w1T,
    const float* __restrict__ by1, const float* __restrict__ Wy2,
    const float* __restrict__ by2, const float* __restrict__ zi_out,
    float* __restrict__ out)
{
  __shared__ float sazt[16][DZ];
  __shared__ float sred[8][16];
  const int tid = threadIdx.x;
  const int n0 = blockIdx.x * 16;
  for (int i = tid; i < 16*DZ; i += 512)
    sazt[i >> 6][i & 63] = azt[(size_t)(n0 + (i >> 6))*DZ + (i & 63)];
  __syncthreads();
  const int w = tid >> 6, lane = tid & 63;
  const int jA = w*128 + lane, jB = jA + 64;
  float repA[16] = {}, repB[16] = {};
#pragma unroll 4
  for (int d4 = 0; d4 < 16; ++d4){
    const float* wrow = w1T + (size_t)(d4*4) * KD;
    const float wa0 = wrow[jA],        wb0 = wrow[jB];
    const float wa1 = wrow[KD + jA],   wb1 = wrow[KD + jB];
    const float wa2 = wrow[2*KD + jA], wb2 = wrow[2*KD + jB];
    const float wa3 = wrow[3*KD + jA], wb3 = wrow[3*KD + jB];
#pragma unroll
    for (int n = 0; n < 16; ++n){
      float4 av = *(const float4*)&sazt[n][d4*4];
      repA[n] += av.x*wa0 + av.y*wa1 + av.z*wa2 + av.w*wa3;
      repB[n] += av.x*wb0 + av.y*wb1 + av.z*wb2 + av.w*wb3;
    }
  }
  const float addA = by1[jA] + Wy2[jA];
  const float addB = by1[jB] + Wy2[jB];
  const size_t zbA = (size_t)(w*2    ) * (NI*DZ) + lane;
  const size_t zbB = (size_t)(w*2 + 1) * (NI*DZ) + lane;
#pragma unroll
  for (int n = 0; n < 16; ++n){
    const size_t ro = (size_t)(n0 + n) * DZ;
    float p = (repA[n] + addA) * zi_out[zbA + ro]
            + (repB[n] + addB) * zi_out[zbB + ro];
    p = wred64(p);
    if (lane == 0) sred[w][n] = p;
  }
  __syncthreads();
  if (tid < 16){
    float s = by2[0];
#pragma unroll
    for (int ww = 0; ww < 8; ++ww) s += sred[ww][tid];
    out[O_MU_Y + n0 + tid] = s;
    out[O_LV_Y + n0 + tid] = 1.0f;
  }
}

extern "C" void kernel_launch(void* const* d_in, const int* in_sizes, int n_in,
                              void* d_out, int out_size, void* d_ws, size_t ws_size,
                              hipStream_t stream)
{
  (void)in_sizes; (void)n_in; (void)out_size; (void)ws_size;
  const float* ins   = (const float*)d_in[0];
  const float* treat = (const float*)d_in[1];
  const float* Wmzt  = (const float*)d_in[2];
  const float* bmzt  = (const float*)d_in[3];
  const float* Wlzt  = (const float*)d_in[4];
  const float* blzt  = (const float*)d_in[5];
  const float* Warec = (const float*)d_in[6];
  const float* barec = (const float*)d_in[7];
  const float* Wmzi  = (const float*)d_in[8];
  const float* bmzi  = (const float*)d_in[9];
  const float* Wlzi  = (const float*)d_in[10];
  const float* blzi  = (const float*)d_in[11];
  const float* mu_p  = (const float*)d_in[12];
  const float* lv_p  = (const float*)d_in[13];
  const float* Wy1   = (const float*)d_in[14];
  const float* by1   = (const float*)d_in[15];
  const float* Wy2   = (const float*)d_in[16];
  const float* by2   = (const float*)d_in[17];
  float* out = (float*)d_out;
  float* wsf = (float*)d_ws;
  ushort_t* wsu = (ushort_t*)(wsf + WSF_END);

  float* ws_zt  = wsf + WSF_ZT;
  float* ws_c   = wsf + WSF_C;
  float* ws_cT  = wsf + WSF_CT;
  float* ws_azt = wsf + WSF_AZT;
  ushort_t* ztb  = wsu + WSU_ZTB;
  ushort_t* Bc   = wsu + WSU_BC;
  ushort_t* zib  = wsu + WSU_ZIB;
  ushort_t* insb = wsu + WSU_INSB;
  ushort_t* zhT  = wsu + WSU_ZHT;
  ushort_t* zlT  = wsu + WSU_ZLT;
  ushort_t* wbh  = wsu + WSU_WBH;
  ushort_t* wbl  = wsu + WSU_WBL;
  float* w1T     = (float*)(wsu + WSU_END);   // [DZ*KD] fp32 (4B-aligned)

  k_prep0   <<<2132, 256, 0, stream>>>(ins, Wy1, Wmzt, Wlzt, mu_p, lv_p, insb, w1T, wbh, wbl, out);
  k_encode_t<<<NT/16, 512, 0, stream>>>(treat, wbh, wbl, bmzt, blzt, out, ws_zt);
  k_qc      <<<NT/4, 256, 0, stream>>>(mu_p, ws_zt, out, ws_c, ws_cT);
  k_prep1   <<<2112, 256, 0, stream>>>(Wmzi, Wlzi, ws_cT, ws_zt, Bc, ztb, zhT, zlT);
  k_encode_i<<<dim3(32, 32), 256, 0, stream>>>(insb, Bc, bmzi, blzi, out, zib);
  k_decoder <<<dim3(32, 32), 256, 0, stream>>>(ztb, zib, ws_c, out);
  k_arec    <<<NT/8, 512, 0, stream>>>(ws_zt, Warec, barec, out);
  k_azt     <<<NI/16, 512, 0, stream>>>(ins, zhT, zlT, ws_azt);
  k_muy     <<<NI/16, 512, 0, stream>>>(ws_azt, w1T, by1, Wy2, by2, out + O_ZI, out);
}

// Round 12
// 375.386 us; speedup vs baseline: 1.0086x; 1.0086x over previous
//
#include <hip/hip_runtime.h>

typedef unsigned short ushort_t;
typedef unsigned int   uint32;
typedef __attribute__((ext_vector_type(8))) short short8;
typedef __attribute__((ext_vector_type(4))) float f32x4;

#define DEV __device__ __forceinline__

// ---- problem dims ----
#define KC 16
#define DZ 64
#define DT 1024
#define NT 2048
#define NI 4096
#define KD 1024   // K*DZ

// ---- output element offsets (return-order concat, float32) ----
#define O_MU_ZT   0
#define O_LV_ZT   131072
#define O_MU_P    262144
#define O_LV_P    263168
#define O_CATES   264192
#define O_MU_ZI   296960
#define O_LV_ZI   4491264
#define O_ZI      8685568
#define O_APRED   12879872
#define O_MU_Y    21268480
#define O_LV_Y    21272576
#define O_AREC    21276672

// ---- workspace layout (floats) ----
#define WSF_ZT   0          // [NT*DZ]
#define WSF_C    131072     // [NT*KC]   c_sample (double softmax)
#define WSF_CT   163840     // [KC*NT]   c_sample transposed
#define WSF_AZT  196608     // [NI*DZ]
#define WSF_END  458752
// ushort region starts at WSF_END floats
#define WSU_ZTB  0          // [NT*DZ]   zt bf16
#define WSU_BC   131072     // [2048*NT] Bc bf16
#define WSU_ZIB  4325376    // [KC*NI*DZ] zi bf16
#define WSU_INSB 8519680    // [NI*NT]   ins bf16
#define WSU_ZHT  16908288   // [DZ*NT]   zt^T hi bf16
#define WSU_ZLT  17039360   // [DZ*NT]   zt^T lo bf16
#define WSU_WBH  17170432   // [128*DT]  [Wmu_zt;Wlv_zt] hi bf16
#define WSU_WBL  17301504   // [128*DT]  [Wmu_zt;Wlv_zt] lo bf16
#define WSU_END  17432576   // end of ushort region; W1T floats start here

DEV ushort_t f2b(float f){
  uint32 u = __float_as_uint(f);
  u += 0x7fffu + ((u >> 16) & 1u);   // RNE
  return (ushort_t)(u >> 16);
}
DEV uint32 pk(float lo, float hi){  // truncating bf16 pack (2 VALU ops)
  return (__float_as_uint(hi) & 0xffff0000u) | (__float_as_uint(lo) >> 16);
}
DEV float wred64(float v){
#pragma unroll
  for (int m = 32; m; m >>= 1) v += __shfl_xor(v, m, 64);
  return v;
}
DEV float fastrcp(float x){ return __builtin_amdgcn_rcpf(x); }  // v_rcp_f32, ~1ulp
// async global->LDS, 16B per lane (dest = wave-uniform base + lane*16)
DEV void gl2lds16(ushort_t* l, const ushort_t* g){
  __builtin_amdgcn_global_load_lds(
      (const __attribute__((address_space(1))) unsigned int*)g,
      (__attribute__((address_space(3))) unsigned int*)l, 16, 0, 0);
}

// ---------------- P0: dep-free prep — insb bf16, Wy1^T, W_zt hi/lo split, copies ----------------
__global__ __launch_bounds__(256) void k_prep0(
    const float* __restrict__ ins, const float* __restrict__ Wy1,
    const float* __restrict__ Wmzt, const float* __restrict__ Wlzt,
    const float* __restrict__ mu_p, const float* __restrict__ lv_p,
    ushort_t* __restrict__ insb, float* __restrict__ w1T,
    ushort_t* __restrict__ wbh, ushort_t* __restrict__ wbl,
    float* __restrict__ out)
{
  const int bx = blockIdx.x, tid = threadIdx.x;
  if (bx < 2048){
    const int g = bx * 256 + tid;            // 0..524287
    const int base = g * 16;                 // NI*NT = 8388608
    const float4* src = (const float4*)(ins + base);
    float4 z0 = src[0], z1 = src[1], z2 = src[2], z3 = src[3];
    ushort_t v[16];
    v[0]=f2b(z0.x); v[1]=f2b(z0.y); v[2]=f2b(z0.z); v[3]=f2b(z0.w);
    v[4]=f2b(z1.x); v[5]=f2b(z1.y); v[6]=f2b(z1.z); v[7]=f2b(z1.w);
    v[8]=f2b(z2.x); v[9]=f2b(z2.y); v[10]=f2b(z2.z); v[11]=f2b(z2.w);
    v[12]=f2b(z3.x); v[13]=f2b(z3.y); v[14]=f2b(z3.z); v[15]=f2b(z3.w);
    *(uint4*)(insb + base) = *(uint4*)&v[0];
    *(uint4*)(insb + base + 8) = *(uint4*)&v[8];
  } else if (bx < 2064){
    // Wy1^T: block handles 64 j-rows x 64 d -> w1T[d][j] (LDS transpose)
    __shared__ float wsh[64 * 65];
    const int j0 = (bx - 2048) * 64;
#pragma unroll
    for (int jj = 0; jj < 16; ++jj){
      const int idx = jj * 256 + tid;
      const int r = idx >> 6, d = idx & 63;
      wsh[r * 65 + d] = Wy1[(size_t)(j0 + r) * DZ + d];
    }
    __syncthreads();
    const int d = tid >> 2, q = tid & 3;
    float v[16];
#pragma unroll
    for (int i = 0; i < 16; ++i) v[i] = wsh[(q*16 + i)*65 + d];
#pragma unroll
    for (int i = 0; i < 4; ++i){
      float4 o; o.x = v[i*4]; o.y = v[i*4+1]; o.z = v[i*4+2]; o.w = v[i*4+3];
      *(float4*)&w1T[(size_t)d * KD + j0 + q*16 + i*4] = o;
    }
  } else if (bx < 2128){
    // [Wmu_zt;Wlv_zt] hi/lo bf16 split: rows 0..63 = mu, 64..127 = lv (no transpose)
    const int idx = (bx - 2064) * 2048 + tid * 8;   // 0..131071
    const int row = idx >> 10, k = idx & 1023;
    const float* src = (row < 64 ? Wmzt + (size_t)row * DT
                                 : Wlzt + (size_t)(row - 64) * DT) + k;
    float4 a0 = *(const float4*)src, a1 = *(const float4*)(src + 4);
    float f[8] = {a0.x, a0.y, a0.z, a0.w, a1.x, a1.y, a1.z, a1.w};
    ushort_t vh[8], vl[8];
#pragma unroll
    for (int i = 0; i < 8; ++i){
      const uint32 u = __float_as_uint(f[i]);
      vh[i] = (ushort_t)(u >> 16);
      const float hf = __uint_as_float(u & 0xffff0000u);
      vl[i] = (ushort_t)(__float_as_uint(f[i] - hf) >> 16);
    }
    *(uint4*)(wbh + (size_t)row * DT + k) = *(uint4*)vh;
    *(uint4*)(wbl + (size_t)row * DT + k) = *(uint4*)vl;
  } else {
    const int i = (bx - 2128) * 256 + tid;   // 0..1023
    out[O_MU_P + i] = mu_p[i];
    out[O_LV_P + i] = lv_p[i];
  }
}

// ---------------- A: encode_t — compensated bf16 MFMA GEMM, split-K 8 waves.
//   Epilogue also emits ztb (bf16) and zhT/zlT (transposed hi/lo split) —
//   bit-identical to the old prep1 branches, saving a zt re-read + 64 blocks. ----
__global__ __launch_bounds__(512) void k_encode_t(
    const float* __restrict__ treat, const ushort_t* __restrict__ wbh,
    const ushort_t* __restrict__ wbl, const float* __restrict__ bmu,
    const float* __restrict__ blv, float* __restrict__ out,
    float* __restrict__ ws_zt, ushort_t* __restrict__ ztb,
    ushort_t* __restrict__ zhT, ushort_t* __restrict__ zlT)
{
  __shared__ float red[16 * 128];
  const int tid = threadIdx.x;
  const int n0 = blockIdx.x * 16;
  const int w = tid >> 6, lane = tid & 63;
  const int kh = w >> 2, wd = w & 3;       // kh: K-half; wd: col-quadrant
  const int l16 = lane & 15, quad = lane >> 4;
  const float* aRow = treat + (size_t)(n0 + l16) * DT + kh * 512 + quad * 8;
  const int colA = wd * 16 + l16;          // mu col 0..63; lv col = colA+64
  const ushort_t* bhA = wbh + (size_t)colA * DT + kh * 512 + quad * 8;
  const ushort_t* blA = wbl + (size_t)colA * DT + kh * 512 + quad * 8;
  const ushort_t* bhB = wbh + (size_t)(colA + 64) * DT + kh * 512 + quad * 8;
  const ushort_t* blB = wbl + (size_t)(colA + 64) * DT + kh * 512 + quad * 8;
  f32x4 accA = {}, accB = {};
#pragma unroll 4
  for (int kt = 0; kt < 16; ++kt){
    const int ko = kt * 32;
    float4 a0 = *(const float4*)(aRow + ko);
    float4 a1 = *(const float4*)(aRow + ko + 4);
    uint32 u0 = __float_as_uint(a0.x), u1 = __float_as_uint(a0.y);
    uint32 u2 = __float_as_uint(a0.z), u3 = __float_as_uint(a0.w);
    uint32 u4 = __float_as_uint(a1.x), u5 = __float_as_uint(a1.y);
    uint32 u6 = __float_as_uint(a1.z), u7 = __float_as_uint(a1.w);
    uint4 H, L;
    H.x = (u1 & 0xffff0000u) | (u0 >> 16);
    H.y = (u3 & 0xffff0000u) | (u2 >> 16);
    H.z = (u5 & 0xffff0000u) | (u4 >> 16);
    H.w = (u7 & 0xffff0000u) | (u6 >> 16);
    float l0 = a0.x - __uint_as_float(u0 & 0xffff0000u);
    float l1 = a0.y - __uint_as_float(u1 & 0xffff0000u);
    float l2 = a0.z - __uint_as_float(u2 & 0xffff0000u);
    float l3 = a0.w - __uint_as_float(u3 & 0xffff0000u);
    float l4 = a1.x - __uint_as_float(u4 & 0xffff0000u);
    float l5 = a1.y - __uint_as_float(u5 & 0xffff0000u);
    float l6 = a1.z - __uint_as_float(u6 & 0xffff0000u);
    float l7 = a1.w - __uint_as_float(u7 & 0xffff0000u);
    L.x = pk(l0, l1); L.y = pk(l2, l3); L.z = pk(l4, l5); L.w = pk(l6, l7);
    short8 ah = *(short8*)&H, al = *(short8*)&L;
    short8 hA = *(const short8*)(bhA + ko), lA = *(const short8*)(blA + ko);
    short8 hB = *(const short8*)(bhB + ko), lB = *(const short8*)(blB + ko);
    accA = __builtin_amdgcn_mfma_f32_16x16x32_bf16(ah, hA, accA, 0, 0, 0);
    accA = __builtin_amdgcn_mfma_f32_16x16x32_bf16(al, hA, accA, 0, 0, 0);
    accA = __builtin_amdgcn_mfma_f32_16x16x32_bf16(ah, lA, accA, 0, 0, 0);
    accB = __builtin_amdgcn_mfma_f32_16x16x32_bf16(ah, hB, accB, 0, 0, 0);
    accB = __builtin_amdgcn_mfma_f32_16x16x32_bf16(al, hB, accB, 0, 0, 0);
    accB = __builtin_amdgcn_mfma_f32_16x16x32_bf16(ah, lB, accB, 0, 0, 0);
  }
  if (kh == 1){
#pragma unroll
    for (int reg = 0; reg < 4; ++reg){
      red[(quad*4 + reg)*128 + colA]      = accA[reg];
      red[(quad*4 + reg)*128 + colA + 64] = accB[reg];
    }
  }
  __syncthreads();
  if (kh == 0){
    const float bA = bmu[colA], bB = blv[colA];
#pragma unroll
    for (int reg = 0; reg < 4; ++reg){
      const int row = n0 + quad*4 + reg;
      const float vA = accA[reg] + red[(quad*4 + reg)*128 + colA] + bA;
      const float vB = accB[reg] + red[(quad*4 + reg)*128 + colA + 64] + bB;
      out[O_MU_ZT + row*DZ + colA] = vA;
      ws_zt[row*DZ + colA] = vA;
      out[O_LV_ZT + row*DZ + colA] = vB;
      // folded prep: zt bf16 copy + transposed hi/lo split (identical math)
      ztb[row*DZ + colA] = f2b(vA);
      const uint32 u = __float_as_uint(vA);
      zhT[(size_t)colA*NT + row] = (ushort_t)(u >> 16);
      const float hf = __uint_as_float(u & 0xffff0000u);
      zlT[(size_t)colA*NT + row] = (ushort_t)(__float_as_uint(vA - hf) >> 16);
    }
  }
}

// ---------------- B: qc -> cates -> c_sample ----------------
__global__ __launch_bounds__(256) void k_qc(
    const float* __restrict__ mu_p, const float* __restrict__ ws_zt,
    float* __restrict__ out, float* __restrict__ ws_c, float* __restrict__ ws_cT)
{
  const int tid = threadIdx.x, lane = tid & 63;
  const int row = blockIdx.x * 4 + (tid >> 6);
  const float z = ws_zt[row * DZ + lane];
  const float nz = sqrtf(wred64(z * z));
  float myqc = 0.f;
#pragma unroll
  for (int k = 0; k < KC; ++k){
    float cv  = 5.f * mu_p[k * DZ + lane];
    float dot = wred64(z * cv);
    float nc2 = wred64(cv * cv);
    float qc  = 10.f * dot / fmaxf(nz * sqrtf(nc2), 1e-6f);
    if (lane == k) myqc = qc;
  }
  float mx = myqc;
#pragma unroll
  for (int m = 8; m; m >>= 1) mx = fmaxf(mx, __shfl_xor(mx, m, 16));
  float e = __expf(myqc - mx);
  float s = e;
#pragma unroll
  for (int m = 8; m; m >>= 1) s += __shfl_xor(s, m, 16);
  float cates = e / s;
  float mx2 = cates;
#pragma unroll
  for (int m = 8; m; m >>= 1) mx2 = fmaxf(mx2, __shfl_xor(mx2, m, 16));
  float e2 = __expf(cates - mx2);
  float s2 = e2;
#pragma unroll
  for (int m = 8; m; m >>= 1) s2 += __shfl_xor(s2, m, 16);
  float c2 = e2 / s2;
  if (lane < KC){
    out[O_CATES + row * KC + lane] = cates;
    ws_c[row * KC + lane] = c2;
    ws_cT[lane * NT + row] = c2;
  }
}

// ---------------- P1: zt-dependent prep — Bc bf16 only (rest folded into encode_t) ----
__global__ __launch_bounds__(256) void k_prep1(
    const float* __restrict__ Wmu, const float* __restrict__ Wlv,
    const float* __restrict__ cT, ushort_t* __restrict__ Bc)
{
  const int j = blockIdx.x, tid = threadIdx.x;
  const bool isMu = j < KD;
  const int kk = (j & (KD-1)) >> 6, d = j & 63;
  const float* W = (isMu ? Wmu : Wlv) + (size_t)d * NT;
  const float* c = cT + (size_t)kk * NT;
  const int t = tid * 8;
  float4 w0 = *(const float4*)(W + t), w1 = *(const float4*)(W + t + 4);
  float4 c0 = *(const float4*)(c + t), c1 = *(const float4*)(c + t + 4);
  ushort_t v[8];
  v[0]=f2b(w0.x*c0.x); v[1]=f2b(w0.y*c0.y); v[2]=f2b(w0.z*c0.z); v[3]=f2b(w0.w*c0.w);
  v[4]=f2b(w1.x*c1.x); v[5]=f2b(w1.y*c1.y); v[6]=f2b(w1.z*c1.z); v[7]=f2b(w1.w*c1.w);
  *(uint4*)(Bc + (size_t)j * NT + t) = *(uint4*)v;
}

// ---------------- C: encode_i — MFMA GEMM, 128x128 tile, BK=64, single-buffer,
//   global_load_lds width-16, T2 XOR-swizzled LDS. (128x64 tile was neutral;
//   reverted to the structure with known-good counters.) ----------------
__global__ __launch_bounds__(256) void k_encode_i(
    const ushort_t* __restrict__ insb, const ushort_t* __restrict__ Bc,
    const float* __restrict__ bmu, const float* __restrict__ blv,
    float* __restrict__ out, ushort_t* __restrict__ zib)
{
  __shared__ ushort_t As[128*64];   // [row][k], 16B-chunk XOR-swizzled by (row&7)
  __shared__ ushort_t Bs[128*64];
  const int tid = threadIdx.x;
  const int j0 = blockIdx.x * 128, n0 = blockIdx.y * 128;
  const int w = tid >> 6, lane = tid & 63;
  const int wm = w & 1, wn = w >> 1;
  const int l16 = lane & 15, quad = lane >> 4;

  const int srow = tid >> 3, schunk = (tid & 7) ^ (srow & 7);
  const ushort_t* aSrc = insb + (size_t)(n0 + srow) * NT + schunk * 8;
  const ushort_t* bSrc = Bc  + (size_t)(j0 + srow) * NT + schunk * 8;
  ushort_t* aDst = &As[tid * 8];
  ushort_t* bDst = &Bs[tid * 8];

  f32x4 acc[4][4] = {};

  for (int kt = 0; kt < NT/64; ++kt){
    const ushort_t* ak = aSrc + kt * 64;
    const ushort_t* bk = bSrc + kt * 64;
#pragma unroll
    for (int i = 0; i < 4; ++i){
      gl2lds16(aDst + i * 2048, ak + (size_t)i * 32 * NT);
      gl2lds16(bDst + i * 2048, bk + (size_t)i * 32 * NT);
    }
    __syncthreads();
#pragma unroll
    for (int ks = 0; ks < 2; ++ks){
      const int rsw = ((ks*4 + quad) ^ (l16 & 7)) * 8;
      short8 af[4], bf[4];
#pragma unroll
      for (int mf = 0; mf < 4; ++mf)
        af[mf] = *(const short8*)&As[(wm*64 + mf*16 + l16)*64 + rsw];
#pragma unroll
      for (int nf = 0; nf < 4; ++nf)
        bf[nf] = *(const short8*)&Bs[(wn*64 + nf*16 + l16)*64 + rsw];
#pragma unroll
      for (int mf = 0; mf < 4; ++mf)
#pragma unroll
        for (int nf = 0; nf < 4; ++nf)
          acc[mf][nf] = __builtin_amdgcn_mfma_f32_16x16x32_bf16(af[mf], bf[nf], acc[mf][nf], 0, 0, 0);
    }
    __syncthreads();
  }

  const int colW = j0 + wn * 64;
  const bool isMu = colW < KD;
  const int kk = (colW & (KD - 1)) >> 6;
  const float* bias = isMu ? bmu : blv;
  const size_t zbase = (size_t)kk * (NI * DZ);
#pragma unroll
  for (int mf = 0; mf < 4; ++mf){
    const int r = n0 + wm*64 + mf*16 + quad*4;
#pragma unroll
    for (int nf = 0; nf < 4; ++nf){
      const int d = nf*16 + l16;
      const float bv = bias[d];
#pragma unroll
      for (int reg = 0; reg < 4; ++reg){
        float v = acc[mf][nf][reg] + bv;
        size_t idx = zbase + (size_t)(r + reg)*DZ + d;
        if (isMu){
          out[O_MU_ZI + idx] = v;
          out[O_ZI + idx] = v;
          zib[idx] = f2b(v);
        } else {
          out[O_LV_ZI + idx] = v;
        }
      }
    }
  }
}

// ---------------- D: decoder — per-k MFMA, 128x64 tile, XOR-swizzled LDS,
//   k-invariant Zt fragments hoisted to registers, rcp sigmoid ----------------
__global__ __launch_bounds__(256) void k_decoder(
    const ushort_t* __restrict__ ztb, const ushort_t* __restrict__ zib,
    const float* __restrict__ ws_c, float* __restrict__ out)
{
  __shared__ ushort_t Zt[64*64];    // [t][64d], 16B-chunk XOR-swizzled by (row&7)
  __shared__ ushort_t Zi[128*64];   // [n][64d], 16B-chunk XOR-swizzled by (row&7)
  __shared__ float ct[64*17];       // c_sample, padded
  const int tid = threadIdx.x;
  const int t0 = blockIdx.x * 64, n0 = blockIdx.y * 128;
  const int w = tid >> 6, lane = tid & 63;
  const int wm = w & 1, wn = w >> 1;
  const int l16 = lane & 15, quad = lane >> 4;
  const int zr = tid >> 2, zq = tid & 3;   // Zt: 4 threads/row, 16 shorts each
  const int ir = tid >> 1, ih = tid & 1;   // Zi: 2 threads/row, 32 shorts each
  {
    const uint4* src = (const uint4*)(ztb + (size_t)(t0 + zr)*DZ + zq*16);
    uint4 z0 = src[0], z1 = src[1];
    ushort_t* dst = &Zt[zr*64];
    *(uint4*)&dst[((zq*2 + 0) ^ (zr & 7)) * 8] = z0;
    *(uint4*)&dst[((zq*2 + 1) ^ (zr & 7)) * 8] = z1;
  }
  for (int i = tid; i < 64*16; i += 256){
    int t = i >> 4, k = i & 15;
    ct[t*17 + k] = ws_c[(size_t)(t0 + t)*KC + k];
  }
  __syncthreads();   // Zt + ct visible
  short8 bfh[2][2];
#pragma unroll
  for (int ks = 0; ks < 2; ++ks){
    const int rsw = ((ks*4 + quad) ^ (l16 & 7)) * 8;
#pragma unroll
    for (int nf = 0; nf < 2; ++nf)
      bfh[ks][nf] = *(const short8*)&Zt[(wn*32 + nf*16 + l16)*64 + rsw];
  }
  const ushort_t* iG = zib + (size_t)(n0 + ir)*DZ + ih*32;
  ushort_t* isw = &Zi[ir*64];
  const int sw0 = ((ih*4 + 0) ^ (ir & 7)) * 8;
  const int sw1 = ((ih*4 + 1) ^ (ir & 7)) * 8;
  const int sw2 = ((ih*4 + 2) ^ (ir & 7)) * 8;
  const int sw3 = ((ih*4 + 3) ^ (ir & 7)) * 8;
  uint4 Zr0, Zr1, Zr2, Zr3;
  {
    const uint4* zp = (const uint4*)iG;
    Zr0 = zp[0]; Zr1 = zp[1]; Zr2 = zp[2]; Zr3 = zp[3];
  }
  f32x4 accum[4][2] = {};
  for (int k = 0; k < KC; ++k){
    __syncthreads();
    *(uint4*)&isw[sw0] = Zr0; *(uint4*)&isw[sw1] = Zr1;
    *(uint4*)&isw[sw2] = Zr2; *(uint4*)&isw[sw3] = Zr3;
    __syncthreads();
    if (k < KC - 1){
      const uint4* zp = (const uint4*)(iG + (size_t)(k+1)*(NI*DZ));
      Zr0 = zp[0]; Zr1 = zp[1]; Zr2 = zp[2]; Zr3 = zp[3];
    }
    f32x4 s[4][2] = {};
#pragma unroll
    for (int ks = 0; ks < 2; ++ks){
      const int rsw = ((ks*4 + quad) ^ (l16 & 7)) * 8;
      short8 af[4];
#pragma unroll
      for (int mf = 0; mf < 4; ++mf)
        af[mf] = *(const short8*)&Zi[(wm*64 + mf*16 + l16)*64 + rsw];
#pragma unroll
      for (int mf = 0; mf < 4; ++mf)
#pragma unroll
        for (int nf = 0; nf < 2; ++nf)
          s[mf][nf] = __builtin_amdgcn_mfma_f32_16x16x32_bf16(af[mf], bfh[ks][nf], s[mf][nf], 0, 0, 0);
    }
#pragma unroll
    for (int nf = 0; nf < 2; ++nf){
      const float cv = ct[(wn*32 + nf*16 + l16)*17 + k];
#pragma unroll
      for (int mf = 0; mf < 4; ++mf)
#pragma unroll
        for (int reg = 0; reg < 4; ++reg)
          accum[mf][nf][reg] += cv * fastrcp(1.f + __expf(-s[mf][nf][reg]));
    }
  }
#pragma unroll
  for (int mf = 0; mf < 4; ++mf){
    const int r = n0 + wm*64 + mf*16 + quad*4;
#pragma unroll
    for (int nf = 0; nf < 2; ++nf){
      const int col = t0 + wn*32 + nf*16 + l16;
#pragma unroll
      for (int reg = 0; reg < 4; ++reg)
        out[O_APRED + (size_t)(r + reg)*NT + col] = accum[mf][nf][reg];
    }
  }
}

// ---------------- E: a_reconst — 8 rows/block, 512 threads (2 j-rows/thread) ----------------
__global__ __launch_bounds__(512) void k_arec(
    const float* __restrict__ ws_zt, const float* __restrict__ W,
    const float* __restrict__ bias, float* __restrict__ out)
{
  __shared__ float zsh[8 * DZ];
  const int n0 = blockIdx.x * 8, tid = threadIdx.x;
  if (tid < 128)
    ((float4*)zsh)[tid] = ((const float4*)(ws_zt + (size_t)n0 * DZ))[tid];
  __syncthreads();
#pragma unroll
  for (int jo = 0; jo < 2; ++jo){
    const int j = jo*512 + tid;
    const float4* w4 = (const float4*)(W + (size_t)j * DZ);
    const float b = bias[j];
    float acc[8];
#pragma unroll
    for (int r = 0; r < 8; ++r) acc[r] = b;
#pragma unroll
    for (int i = 0; i < 16; ++i){
      float4 wv = w4[i];
#pragma unroll
      for (int r = 0; r < 8; ++r){
        const float* z = &zsh[r*DZ + i*4];
        acc[r] += wv.x*z[0] + wv.y*z[1] + wv.z*z[2] + wv.w*z[3];
      }
    }
#pragma unroll
    for (int r = 0; r < 8; ++r)
      out[O_AREC + (size_t)(n0 + r)*DT + j] = fastrcp(1.f + __expf(-acc[r]));
  }
}

// ---------------- F1: a_zt = ins @ zt — compensated bf16 MFMA, 4-way split-K,
//   1024 threads (4 waves/SIMD; was 2 — latency-bound at 1 block/CU) ----------
__global__ __launch_bounds__(1024) void k_azt(
    const float* __restrict__ ins, const ushort_t* __restrict__ zhT,
    const ushort_t* __restrict__ zlT, float* __restrict__ azt)
{
  __shared__ float red[3 * 16 * 64];
  const int tid = threadIdx.x;
  const int n0 = blockIdx.x * 16;
  const int w = tid >> 6, lane = tid & 63;
  const int kh = w >> 2, wd = w & 3;       // kh: K-quarter (0..3); wd: d-quadrant
  const int l16 = lane & 15, quad = lane >> 4;
  const float* aRow = ins + (size_t)(n0 + l16) * NT + kh * 512 + quad * 8;
  const ushort_t* bh = zhT + (size_t)(wd * 16 + l16) * NT + kh * 512 + quad * 8;
  const ushort_t* bl = zlT + (size_t)(wd * 16 + l16) * NT + kh * 512 + quad * 8;
  f32x4 acc = {};
#pragma unroll 4
  for (int kt = 0; kt < 8; ++kt){
#pragma unroll
    for (int ks = 0; ks < 2; ++ks){
      const int ko = kt * 64 + ks * 32;
      float4 a0 = *(const float4*)(aRow + ko);
      float4 a1 = *(const float4*)(aRow + ko + 4);
      uint32 u0 = __float_as_uint(a0.x), u1 = __float_as_uint(a0.y);
      uint32 u2 = __float_as_uint(a0.z), u3 = __float_as_uint(a0.w);
      uint32 u4 = __float_as_uint(a1.x), u5 = __float_as_uint(a1.y);
      uint32 u6 = __float_as_uint(a1.z), u7 = __float_as_uint(a1.w);
      uint4 H, L;
      H.x = (u1 & 0xffff0000u) | (u0 >> 16);
      H.y = (u3 & 0xffff0000u) | (u2 >> 16);
      H.z = (u5 & 0xffff0000u) | (u4 >> 16);
      H.w = (u7 & 0xffff0000u) | (u6 >> 16);
      float l0 = a0.x - __uint_as_float(u0 & 0xffff0000u);
      float l1 = a0.y - __uint_as_float(u1 & 0xffff0000u);
      float l2 = a0.z - __uint_as_float(u2 & 0xffff0000u);
      float l3 = a0.w - __uint_as_float(u3 & 0xffff0000u);
      float l4 = a1.x - __uint_as_float(u4 & 0xffff0000u);
      float l5 = a1.y - __uint_as_float(u5 & 0xffff0000u);
      float l6 = a1.z - __uint_as_float(u6 & 0xffff0000u);
      float l7 = a1.w - __uint_as_float(u7 & 0xffff0000u);
      L.x = pk(l0, l1); L.y = pk(l2, l3); L.z = pk(l4, l5); L.w = pk(l6, l7);
      short8 ah = *(short8*)&H, al = *(short8*)&L;
      short8 bh8 = *(const short8*)(bh + ko);
      short8 bl8 = *(const short8*)(bl + ko);
      acc = __builtin_amdgcn_mfma_f32_16x16x32_bf16(ah, bh8, acc, 0, 0, 0);
      acc = __builtin_amdgcn_mfma_f32_16x16x32_bf16(al, bh8, acc, 0, 0, 0);
      acc = __builtin_amdgcn_mfma_f32_16x16x32_bf16(ah, bl8, acc, 0, 0, 0);
    }
  }
  const int col = wd * 16 + l16;
  if (kh > 0){
#pragma unroll
    for (int reg = 0; reg < 4; ++reg)
      red[(kh-1)*1024 + (quad*4 + reg)*64 + col] = acc[reg];
  }
  __syncthreads();
  if (kh == 0){
#pragma unroll
    for (int reg = 0; reg < 4; ++reg){
      const int idx = (quad*4 + reg)*64 + col;
      azt[(size_t)(n0 + quad*4 + reg) * DZ + col] =
          acc[reg] + red[idx] + red[1024 + idx] + red[2048 + idx];
    }
  }
}

// ---------------- F2: mu_y / logvar_y — coalesced via Wy1^T, 2 j/thread, fp32 ----------------
__global__ __launch_bounds__(512) void k_muy(
    const float* __restrict__ azt, const float* __restrict__ w1T,
    const float* __restrict__ by1, const float* __restrict__ Wy2,
    const float* __restrict__ by2, const float* __restrict__ zi_out,
    float* __restrict__ out)
{
  __shared__ float sazt[16][DZ];
  __shared__ float sred[8][16];
  const int tid = threadIdx.x;
  const int n0 = blockIdx.x * 16;
  for (int i = tid; i < 16*DZ; i += 512)
    sazt[i >> 6][i & 63] = azt[(size_t)(n0 + (i >> 6))*DZ + (i & 63)];
  __syncthreads();
  const int w = tid >> 6, lane = tid & 63;
  const int jA = w*128 + lane, jB = jA + 64;
  float repA[16] = {}, repB[16] = {};
#pragma unroll 4
  for (int d4 = 0; d4 < 16; ++d4){
    const float* wrow = w1T + (size_t)(d4*4) * KD;
    const float wa0 = wrow[jA],        wb0 = wrow[jB];
    const float wa1 = wrow[KD + jA],   wb1 = wrow[KD + jB];
    const float wa2 = wrow[2*KD + jA], wb2 = wrow[2*KD + jB];
    const float wa3 = wrow[3*KD + jA], wb3 = wrow[3*KD + jB];
#pragma unroll
    for (int n = 0; n < 16; ++n){
      float4 av = *(const float4*)&sazt[n][d4*4];
      repA[n] += av.x*wa0 + av.y*wa1 + av.z*wa2 + av.w*wa3;
      repB[n] += av.x*wb0 + av.y*wb1 + av.z*wb2 + av.w*wb3;
    }
  }
  const float addA = by1[jA] + Wy2[jA];
  const float addB = by1[jB] + Wy2[jB];
  const size_t zbA = (size_t)(w*2    ) * (NI*DZ) + lane;
  const size_t zbB = (size_t)(w*2 + 1) * (NI*DZ) + lane;
#pragma unroll
  for (int n = 0; n < 16; ++n){
    const size_t ro = (size_t)(n0 + n) * DZ;
    float p = (repA[n] + addA) * zi_out[zbA + ro]
            + (repB[n] + addB) * zi_out[zbB + ro];
    p = wred64(p);
    if (lane == 0) sred[w][n] = p;
  }
  __syncthreads();
  if (tid < 16){
    float s = by2[0];
#pragma unroll
    for (int ww = 0; ww < 8; ++ww) s += sred[ww][tid];
    out[O_MU_Y + n0 + tid] = s;
    out[O_LV_Y + n0 + tid] = 1.0f;
  }
}

extern "C" void kernel_launch(void* const* d_in, const int* in_sizes, int n_in,
                              void* d_out, int out_size, void* d_ws, size_t ws_size,
                              hipStream_t stream)
{
  (void)in_sizes; (void)n_in; (void)out_size; (void)ws_size;
  const float* ins   = (const float*)d_in[0];
  const float* treat = (const float*)d_in[1];
  const float* Wmzt  = (const float*)d_in[2];
  const float* bmzt  = (const float*)d_in[3];
  const float* Wlzt  = (const float*)d_in[4];
  const float* blzt  = (const float*)d_in[5];
  const float* Warec = (const float*)d_in[6];
  const float* barec = (const float*)d_in[7];
  const float* Wmzi  = (const float*)d_in[8];
  const float* bmzi  = (const float*)d_in[9];
  const float* Wlzi  = (const float*)d_in[10];
  const float* blzi  = (const float*)d_in[11];
  const float* mu_p  = (const float*)d_in[12];
  const float* lv_p  = (const float*)d_in[13];
  const float* Wy1   = (const float*)d_in[14];
  const float* by1   = (const float*)d_in[15];
  const float* Wy2   = (const float*)d_in[16];
  const float* by2   = (const float*)d_in[17];
  float* out = (float*)d_out;
  float* wsf = (float*)d_ws;
  ushort_t* wsu = (ushort_t*)(wsf + WSF_END);

  float* ws_zt  = wsf + WSF_ZT;
  float* ws_c   = wsf + WSF_C;
  float* ws_cT  = wsf + WSF_CT;
  float* ws_azt = wsf + WSF_AZT;
  ushort_t* ztb  = wsu + WSU_ZTB;
  ushort_t* Bc   = wsu + WSU_BC;
  ushort_t* zib  = wsu + WSU_ZIB;
  ushort_t* insb = wsu + WSU_INSB;
  ushort_t* zhT  = wsu + WSU_ZHT;
  ushort_t* zlT  = wsu + WSU_ZLT;
  ushort_t* wbh  = wsu + WSU_WBH;
  ushort_t* wbl  = wsu + WSU_WBL;
  float* w1T     = (float*)(wsu + WSU_END);   // [DZ*KD] fp32 (4B-aligned)

  k_prep0   <<<2132, 256, 0, stream>>>(ins, Wy1, Wmzt, Wlzt, mu_p, lv_p, insb, w1T, wbh, wbl, out);
  k_encode_t<<<NT/16, 512, 0, stream>>>(treat, wbh, wbl, bmzt, blzt, out, ws_zt, ztb, zhT, zlT);
  k_qc      <<<NT/4, 256, 0, stream>>>(mu_p, ws_zt, out, ws_c, ws_cT);
  k_prep1   <<<2048, 256, 0, stream>>>(Wmzi, Wlzi, ws_cT, Bc);
  k_encode_i<<<dim3(16, 32), 256, 0, stream>>>(insb, Bc, bmzi, blzi, out, zib);
  k_decoder <<<dim3(32, 32), 256, 0, stream>>>(ztb, zib, ws_c, out);
  k_arec    <<<NT/8, 512, 0, stream>>>(ws_zt, Warec, barec, out);
  k_azt     <<<NI/16, 1024, 0, stream>>>(ins, zhT, zlT, ws_azt);
  k_muy     <<<NI/16, 512, 0, stream>>>(ws_azt, w1T, by1, Wy2, by2, out + O_ZI, out);
}

// Round 13
// 371.360 us; speedup vs baseline: 1.0195x; 1.0108x over previous
//
#include <hip/hip_runtime.h>

typedef unsigned short ushort_t;
typedef unsigned int   uint32;
typedef __attribute__((ext_vector_type(8))) short short8;
typedef __attribute__((ext_vector_type(4))) float f32x4;

#define DEV __device__ __forceinline__

// ---- problem dims ----
#define KC 16
#define DZ 64
#define DT 1024
#define NT 2048
#define NI 4096
#define KD 1024   // K*DZ

// ---- output element offsets (return-order concat, float32) ----
#define O_MU_ZT   0
#define O_LV_ZT   131072
#define O_MU_P    262144
#define O_LV_P    263168
#define O_CATES   264192
#define O_MU_ZI   296960
#define O_LV_ZI   4491264
#define O_ZI      8685568
#define O_APRED   12879872
#define O_MU_Y    21268480
#define O_LV_Y    21272576
#define O_AREC    21276672

// ---- workspace layout (floats) ----
#define WSF_ZT   0          // [NT*DZ]
#define WSF_C    131072     // [NT*KC]   c_sample (double softmax)
#define WSF_CT   163840     // [KC*NT]   c_sample transposed
#define WSF_AZT  196608     // [NI*DZ]   (unused after fusion; kept for layout)
#define WSF_END  458752
// ushort region starts at WSF_END floats
#define WSU_ZTB  0          // [NT*DZ]   zt bf16
#define WSU_BC   131072     // [2048*NT] Bc bf16
#define WSU_ZIB  4325376    // [KC*NI*DZ] zi bf16
#define WSU_INSB 8519680    // [NI*NT]   ins bf16
#define WSU_ZHT  16908288   // [DZ*NT]   zt^T hi bf16
#define WSU_ZLT  17039360   // [DZ*NT]   zt^T lo bf16
#define WSU_WBH  17170432   // [128*DT]  [Wmu_zt;Wlv_zt] hi bf16
#define WSU_WBL  17301504   // [128*DT]  [Wmu_zt;Wlv_zt] lo bf16
#define WSU_END  17432576   // end of ushort region; W1T floats start here

DEV ushort_t f2b(float f){
  uint32 u = __float_as_uint(f);
  u += 0x7fffu + ((u >> 16) & 1u);   // RNE
  return (ushort_t)(u >> 16);
}
DEV uint32 pk(float lo, float hi){  // truncating bf16 pack (2 VALU ops)
  return (__float_as_uint(hi) & 0xffff0000u) | (__float_as_uint(lo) >> 16);
}
DEV float wred64(float v){
#pragma unroll
  for (int m = 32; m; m >>= 1) v += __shfl_xor(v, m, 64);
  return v;
}
DEV float fastrcp(float x){ return __builtin_amdgcn_rcpf(x); }  // v_rcp_f32, ~1ulp
// async global->LDS, 16B per lane (dest = wave-uniform base + lane*16)
DEV void gl2lds16(ushort_t* l, const ushort_t* g){
  __builtin_amdgcn_global_load_lds(
      (const __attribute__((address_space(1))) unsigned int*)g,
      (__attribute__((address_space(3))) unsigned int*)l, 16, 0, 0);
}

// ---------------- P0: dep-free prep — insb bf16, Wy1^T, W_zt hi/lo split, copies ----------------
__global__ __launch_bounds__(256) void k_prep0(
    const float* __restrict__ ins, const float* __restrict__ Wy1,
    const float* __restrict__ Wmzt, const float* __restrict__ Wlzt,
    const float* __restrict__ mu_p, const float* __restrict__ lv_p,
    ushort_t* __restrict__ insb, float* __restrict__ w1T,
    ushort_t* __restrict__ wbh, ushort_t* __restrict__ wbl,
    float* __restrict__ out)
{
  const int bx = blockIdx.x, tid = threadIdx.x;
  if (bx < 2048){
    const int g = bx * 256 + tid;            // 0..524287
    const int base = g * 16;                 // NI*NT = 8388608
    const float4* src = (const float4*)(ins + base);
    float4 z0 = src[0], z1 = src[1], z2 = src[2], z3 = src[3];
    ushort_t v[16];
    v[0]=f2b(z0.x); v[1]=f2b(z0.y); v[2]=f2b(z0.z); v[3]=f2b(z0.w);
    v[4]=f2b(z1.x); v[5]=f2b(z1.y); v[6]=f2b(z1.z); v[7]=f2b(z1.w);
    v[8]=f2b(z2.x); v[9]=f2b(z2.y); v[10]=f2b(z2.z); v[11]=f2b(z2.w);
    v[12]=f2b(z3.x); v[13]=f2b(z3.y); v[14]=f2b(z3.z); v[15]=f2b(z3.w);
    *(uint4*)(insb + base) = *(uint4*)&v[0];
    *(uint4*)(insb + base + 8) = *(uint4*)&v[8];
  } else if (bx < 2064){
    // Wy1^T: block handles 64 j-rows x 64 d -> w1T[d][j] (LDS transpose)
    __shared__ float wsh[64 * 65];
    const int j0 = (bx - 2048) * 64;
#pragma unroll
    for (int jj = 0; jj < 16; ++jj){
      const int idx = jj * 256 + tid;
      const int r = idx >> 6, d = idx & 63;
      wsh[r * 65 + d] = Wy1[(size_t)(j0 + r) * DZ + d];
    }
    __syncthreads();
    const int d = tid >> 2, q = tid & 3;
    float v[16];
#pragma unroll
    for (int i = 0; i < 16; ++i) v[i] = wsh[(q*16 + i)*65 + d];
#pragma unroll
    for (int i = 0; i < 4; ++i){
      float4 o; o.x = v[i*4]; o.y = v[i*4+1]; o.z = v[i*4+2]; o.w = v[i*4+3];
      *(float4*)&w1T[(size_t)d * KD + j0 + q*16 + i*4] = o;
    }
  } else if (bx < 2128){
    // [Wmu_zt;Wlv_zt] hi/lo bf16 split: rows 0..63 = mu, 64..127 = lv (no transpose)
    const int idx = (bx - 2064) * 2048 + tid * 8;   // 0..131071
    const int row = idx >> 10, k = idx & 1023;
    const float* src = (row < 64 ? Wmzt + (size_t)row * DT
                                 : Wlzt + (size_t)(row - 64) * DT) + k;
    float4 a0 = *(const float4*)src, a1 = *(const float4*)(src + 4);
    float f[8] = {a0.x, a0.y, a0.z, a0.w, a1.x, a1.y, a1.z, a1.w};
    ushort_t vh[8], vl[8];
#pragma unroll
    for (int i = 0; i < 8; ++i){
      const uint32 u = __float_as_uint(f[i]);
      vh[i] = (ushort_t)(u >> 16);
      const float hf = __uint_as_float(u & 0xffff0000u);
      vl[i] = (ushort_t)(__float_as_uint(f[i] - hf) >> 16);
    }
    *(uint4*)(wbh + (size_t)row * DT + k) = *(uint4*)vh;
    *(uint4*)(wbl + (size_t)row * DT + k) = *(uint4*)vl;
  } else {
    const int i = (bx - 2128) * 256 + tid;   // 0..1023
    out[O_MU_P + i] = mu_p[i];
    out[O_LV_P + i] = lv_p[i];
  }
}

// ---------------- A: encode_t — compensated bf16 MFMA GEMM, split-K 8 waves.
//   Epilogue emits ztb + zhT/zlT (folded prep) AND runs qc->cates->c_sample
//   in-block (the 16 zt rows are already resident in LDS — saves a launch
//   + a full zt re-read; qc math is verbatim the old k_qc). ----------------
__global__ __launch_bounds__(512) void k_encode_t(
    const float* __restrict__ treat, const ushort_t* __restrict__ wbh,
    const ushort_t* __restrict__ wbl, const float* __restrict__ bmu,
    const float* __restrict__ blv, const float* __restrict__ mu_p,
    float* __restrict__ out, float* __restrict__ ws_zt,
    ushort_t* __restrict__ ztb, ushort_t* __restrict__ zhT,
    ushort_t* __restrict__ zlT, float* __restrict__ ws_c,
    float* __restrict__ ws_cT)
{
  __shared__ float red[16 * 128];
  __shared__ float zsh[16 * 64];
  const int tid = threadIdx.x;
  const int n0 = blockIdx.x * 16;
  const int w = tid >> 6, lane = tid & 63;
  const int kh = w >> 2, wd = w & 3;       // kh: K-half; wd: col-quadrant
  const int l16 = lane & 15, quad = lane >> 4;
  const float* aRow = treat + (size_t)(n0 + l16) * DT + kh * 512 + quad * 8;
  const int colA = wd * 16 + l16;          // mu col 0..63; lv col = colA+64
  const ushort_t* bhA = wbh + (size_t)colA * DT + kh * 512 + quad * 8;
  const ushort_t* blA = wbl + (size_t)colA * DT + kh * 512 + quad * 8;
  const ushort_t* bhB = wbh + (size_t)(colA + 64) * DT + kh * 512 + quad * 8;
  const ushort_t* blB = wbl + (size_t)(colA + 64) * DT + kh * 512 + quad * 8;
  f32x4 accA = {}, accB = {};
#pragma unroll 4
  for (int kt = 0; kt < 16; ++kt){
    const int ko = kt * 32;
    float4 a0 = *(const float4*)(aRow + ko);
    float4 a1 = *(const float4*)(aRow + ko + 4);
    uint32 u0 = __float_as_uint(a0.x), u1 = __float_as_uint(a0.y);
    uint32 u2 = __float_as_uint(a0.z), u3 = __float_as_uint(a0.w);
    uint32 u4 = __float_as_uint(a1.x), u5 = __float_as_uint(a1.y);
    uint32 u6 = __float_as_uint(a1.z), u7 = __float_as_uint(a1.w);
    uint4 H, L;
    H.x = (u1 & 0xffff0000u) | (u0 >> 16);
    H.y = (u3 & 0xffff0000u) | (u2 >> 16);
    H.z = (u5 & 0xffff0000u) | (u4 >> 16);
    H.w = (u7 & 0xffff0000u) | (u6 >> 16);
    float l0 = a0.x - __uint_as_float(u0 & 0xffff0000u);
    float l1 = a0.y - __uint_as_float(u1 & 0xffff0000u);
    float l2 = a0.z - __uint_as_float(u2 & 0xffff0000u);
    float l3 = a0.w - __uint_as_float(u3 & 0xffff0000u);
    float l4 = a1.x - __uint_as_float(u4 & 0xffff0000u);
    float l5 = a1.y - __uint_as_float(u5 & 0xffff0000u);
    float l6 = a1.z - __uint_as_float(u6 & 0xffff0000u);
    float l7 = a1.w - __uint_as_float(u7 & 0xffff0000u);
    L.x = pk(l0, l1); L.y = pk(l2, l3); L.z = pk(l4, l5); L.w = pk(l6, l7);
    short8 ah = *(short8*)&H, al = *(short8*)&L;
    short8 hA = *(const short8*)(bhA + ko), lA = *(const short8*)(blA + ko);
    short8 hB = *(const short8*)(bhB + ko), lB = *(const short8*)(blB + ko);
    accA = __builtin_amdgcn_mfma_f32_16x16x32_bf16(ah, hA, accA, 0, 0, 0);
    accA = __builtin_amdgcn_mfma_f32_16x16x32_bf16(al, hA, accA, 0, 0, 0);
    accA = __builtin_amdgcn_mfma_f32_16x16x32_bf16(ah, lA, accA, 0, 0, 0);
    accB = __builtin_amdgcn_mfma_f32_16x16x32_bf16(ah, hB, accB, 0, 0, 0);
    accB = __builtin_amdgcn_mfma_f32_16x16x32_bf16(al, hB, accB, 0, 0, 0);
    accB = __builtin_amdgcn_mfma_f32_16x16x32_bf16(ah, lB, accB, 0, 0, 0);
  }
  if (kh == 1){
#pragma unroll
    for (int reg = 0; reg < 4; ++reg){
      red[(quad*4 + reg)*128 + colA]      = accA[reg];
      red[(quad*4 + reg)*128 + colA + 64] = accB[reg];
    }
  }
  __syncthreads();
  if (kh == 0){
    const float bA = bmu[colA], bB = blv[colA];
#pragma unroll
    for (int reg = 0; reg < 4; ++reg){
      const int lrow = quad*4 + reg;
      const int row = n0 + lrow;
      const float vA = accA[reg] + red[lrow*128 + colA] + bA;
      const float vB = accB[reg] + red[lrow*128 + colA + 64] + bB;
      out[O_MU_ZT + row*DZ + colA] = vA;
      ws_zt[row*DZ + colA] = vA;
      out[O_LV_ZT + row*DZ + colA] = vB;
      zsh[lrow*64 + colA] = vA;
      // folded prep: zt bf16 copy + transposed hi/lo split (identical math)
      ztb[row*DZ + colA] = f2b(vA);
      const uint32 u = __float_as_uint(vA);
      zhT[(size_t)colA*NT + row] = (ushort_t)(u >> 16);
      const float hf = __uint_as_float(u & 0xffff0000u);
      zlT[(size_t)colA*NT + row] = (ushort_t)(__float_as_uint(vA - hf) >> 16);
    }
  }
  __syncthreads();
  // ---- qc phase: 8 waves x 2 rows (verbatim old k_qc math) ----
#pragma unroll
  for (int r = 0; r < 2; ++r){
    const int lrow = w*2 + r;
    const int row = n0 + lrow;
    const float z = zsh[lrow*64 + lane];
    const float nz = sqrtf(wred64(z * z));
    float myqc = 0.f;
#pragma unroll
    for (int k = 0; k < KC; ++k){
      float cv  = 5.f * mu_p[k * DZ + lane];
      float dot = wred64(z * cv);
      float nc2 = wred64(cv * cv);
      float qc  = 10.f * dot / fmaxf(nz * sqrtf(nc2), 1e-6f);
      if (lane == k) myqc = qc;
    }
    float mx = myqc;
#pragma unroll
    for (int m = 8; m; m >>= 1) mx = fmaxf(mx, __shfl_xor(mx, m, 16));
    float e = __expf(myqc - mx);
    float s = e;
#pragma unroll
    for (int m = 8; m; m >>= 1) s += __shfl_xor(s, m, 16);
    float cates = e / s;
    float mx2 = cates;
#pragma unroll
    for (int m = 8; m; m >>= 1) mx2 = fmaxf(mx2, __shfl_xor(mx2, m, 16));
    float e2 = __expf(cates - mx2);
    float s2 = e2;
#pragma unroll
    for (int m = 8; m; m >>= 1) s2 += __shfl_xor(s2, m, 16);
    float c2 = e2 / s2;
    if (lane < KC){
      out[O_CATES + row * KC + lane] = cates;
      ws_c[row * KC + lane] = c2;
      ws_cT[lane * NT + row] = c2;
    }
  }
}

// ---------------- P1: zt-dependent prep — Bc bf16 only ----------------
__global__ __launch_bounds__(256) void k_prep1(
    const float* __restrict__ Wmu, const float* __restrict__ Wlv,
    const float* __restrict__ cT, ushort_t* __restrict__ Bc)
{
  const int j = blockIdx.x, tid = threadIdx.x;
  const bool isMu = j < KD;
  const int kk = (j & (KD-1)) >> 6, d = j & 63;
  const float* W = (isMu ? Wmu : Wlv) + (size_t)d * NT;
  const float* c = cT + (size_t)kk * NT;
  const int t = tid * 8;
  float4 w0 = *(const float4*)(W + t), w1 = *(const float4*)(W + t + 4);
  float4 c0 = *(const float4*)(c + t), c1 = *(const float4*)(c + t + 4);
  ushort_t v[8];
  v[0]=f2b(w0.x*c0.x); v[1]=f2b(w0.y*c0.y); v[2]=f2b(w0.z*c0.z); v[3]=f2b(w0.w*c0.w);
  v[4]=f2b(w1.x*c1.x); v[5]=f2b(w1.y*c1.y); v[6]=f2b(w1.z*c1.z); v[7]=f2b(w1.w*c1.w);
  *(uint4*)(Bc + (size_t)j * NT + t) = *(uint4*)v;
}

// ---------------- C: encode_i — MFMA GEMM, 128x128 tile, BK=64, single-buffer,
//   global_load_lds width-16, T2 XOR-swizzled LDS ----------------
__global__ __launch_bounds__(256) void k_encode_i(
    const ushort_t* __restrict__ insb, const ushort_t* __restrict__ Bc,
    const float* __restrict__ bmu, const float* __restrict__ blv,
    float* __restrict__ out, ushort_t* __restrict__ zib)
{
  __shared__ ushort_t As[128*64];   // [row][k], 16B-chunk XOR-swizzled by (row&7)
  __shared__ ushort_t Bs[128*64];
  const int tid = threadIdx.x;
  const int j0 = blockIdx.x * 128, n0 = blockIdx.y * 128;
  const int w = tid >> 6, lane = tid & 63;
  const int wm = w & 1, wn = w >> 1;
  const int l16 = lane & 15, quad = lane >> 4;

  const int srow = tid >> 3, schunk = (tid & 7) ^ (srow & 7);
  const ushort_t* aSrc = insb + (size_t)(n0 + srow) * NT + schunk * 8;
  const ushort_t* bSrc = Bc  + (size_t)(j0 + srow) * NT + schunk * 8;
  ushort_t* aDst = &As[tid * 8];
  ushort_t* bDst = &Bs[tid * 8];

  f32x4 acc[4][4] = {};

  for (int kt = 0; kt < NT/64; ++kt){
    const ushort_t* ak = aSrc + kt * 64;
    const ushort_t* bk = bSrc + kt * 64;
#pragma unroll
    for (int i = 0; i < 4; ++i){
      gl2lds16(aDst + i * 2048, ak + (size_t)i * 32 * NT);
      gl2lds16(bDst + i * 2048, bk + (size_t)i * 32 * NT);
    }
    __syncthreads();
#pragma unroll
    for (int ks = 0; ks < 2; ++ks){
      const int rsw = ((ks*4 + quad) ^ (l16 & 7)) * 8;
      short8 af[4], bf[4];
#pragma unroll
      for (int mf = 0; mf < 4; ++mf)
        af[mf] = *(const short8*)&As[(wm*64 + mf*16 + l16)*64 + rsw];
#pragma unroll
      for (int nf = 0; nf < 4; ++nf)
        bf[nf] = *(const short8*)&Bs[(wn*64 + nf*16 + l16)*64 + rsw];
#pragma unroll
      for (int mf = 0; mf < 4; ++mf)
#pragma unroll
        for (int nf = 0; nf < 4; ++nf)
          acc[mf][nf] = __builtin_amdgcn_mfma_f32_16x16x32_bf16(af[mf], bf[nf], acc[mf][nf], 0, 0, 0);
    }
    __syncthreads();
  }

  const int colW = j0 + wn * 64;
  const bool isMu = colW < KD;
  const int kk = (colW & (KD - 1)) >> 6;
  const float* bias = isMu ? bmu : blv;
  const size_t zbase = (size_t)kk * (NI * DZ);
#pragma unroll
  for (int mf = 0; mf < 4; ++mf){
    const int r = n0 + wm*64 + mf*16 + quad*4;
#pragma unroll
    for (int nf = 0; nf < 4; ++nf){
      const int d = nf*16 + l16;
      const float bv = bias[d];
#pragma unroll
      for (int reg = 0; reg < 4; ++reg){
        float v = acc[mf][nf][reg] + bv;
        size_t idx = zbase + (size_t)(r + reg)*DZ + d;
        if (isMu){
          out[O_MU_ZI + idx] = v;
          out[O_ZI + idx] = v;
          zib[idx] = f2b(v);
        } else {
          out[O_LV_ZI + idx] = v;
        }
      }
    }
  }
}

// ---------------- D: decoder — per-k MFMA, 128x64 tile, XOR-swizzled LDS,
//   k-invariant Zt fragments hoisted to registers, rcp sigmoid ----------------
__global__ __launch_bounds__(256) void k_decoder(
    const ushort_t* __restrict__ ztb, const ushort_t* __restrict__ zib,
    const float* __restrict__ ws_c, float* __restrict__ out)
{
  __shared__ ushort_t Zt[64*64];    // [t][64d], 16B-chunk XOR-swizzled by (row&7)
  __shared__ ushort_t Zi[128*64];   // [n][64d], 16B-chunk XOR-swizzled by (row&7)
  __shared__ float ct[64*17];       // c_sample, padded
  const int tid = threadIdx.x;
  const int t0 = blockIdx.x * 64, n0 = blockIdx.y * 128;
  const int w = tid >> 6, lane = tid & 63;
  const int wm = w & 1, wn = w >> 1;
  const int l16 = lane & 15, quad = lane >> 4;
  const int zr = tid >> 2, zq = tid & 3;   // Zt: 4 threads/row, 16 shorts each
  const int ir = tid >> 1, ih = tid & 1;   // Zi: 2 threads/row, 32 shorts each
  {
    const uint4* src = (const uint4*)(ztb + (size_t)(t0 + zr)*DZ + zq*16);
    uint4 z0 = src[0], z1 = src[1];
    ushort_t* dst = &Zt[zr*64];
    *(uint4*)&dst[((zq*2 + 0) ^ (zr & 7)) * 8] = z0;
    *(uint4*)&dst[((zq*2 + 1) ^ (zr & 7)) * 8] = z1;
  }
  for (int i = tid; i < 64*16; i += 256){
    int t = i >> 4, k = i & 15;
    ct[t*17 + k] = ws_c[(size_t)(t0 + t)*KC + k];
  }
  __syncthreads();   // Zt + ct visible
  short8 bfh[2][2];
#pragma unroll
  for (int ks = 0; ks < 2; ++ks){
    const int rsw = ((ks*4 + quad) ^ (l16 & 7)) * 8;
#pragma unroll
    for (int nf = 0; nf < 2; ++nf)
      bfh[ks][nf] = *(const short8*)&Zt[(wn*32 + nf*16 + l16)*64 + rsw];
  }
  const ushort_t* iG = zib + (size_t)(n0 + ir)*DZ + ih*32;
  ushort_t* isw = &Zi[ir*64];
  const int sw0 = ((ih*4 + 0) ^ (ir & 7)) * 8;
  const int sw1 = ((ih*4 + 1) ^ (ir & 7)) * 8;
  const int sw2 = ((ih*4 + 2) ^ (ir & 7)) * 8;
  const int sw3 = ((ih*4 + 3) ^ (ir & 7)) * 8;
  uint4 Zr0, Zr1, Zr2, Zr3;
  {
    const uint4* zp = (const uint4*)iG;
    Zr0 = zp[0]; Zr1 = zp[1]; Zr2 = zp[2]; Zr3 = zp[3];
  }
  f32x4 accum[4][2] = {};
  for (int k = 0; k < KC; ++k){
    __syncthreads();
    *(uint4*)&isw[sw0] = Zr0; *(uint4*)&isw[sw1] = Zr1;
    *(uint4*)&isw[sw2] = Zr2; *(uint4*)&isw[sw3] = Zr3;
    __syncthreads();
    if (k < KC - 1){
      const uint4* zp = (const uint4*)(iG + (size_t)(k+1)*(NI*DZ));
      Zr0 = zp[0]; Zr1 = zp[1]; Zr2 = zp[2]; Zr3 = zp[3];
    }
    f32x4 s[4][2] = {};
#pragma unroll
    for (int ks = 0; ks < 2; ++ks){
      const int rsw = ((ks*4 + quad) ^ (l16 & 7)) * 8;
      short8 af[4];
#pragma unroll
      for (int mf = 0; mf < 4; ++mf)
        af[mf] = *(const short8*)&Zi[(wm*64 + mf*16 + l16)*64 + rsw];
#pragma unroll
      for (int mf = 0; mf < 4; ++mf)
#pragma unroll
        for (int nf = 0; nf < 2; ++nf)
          s[mf][nf] = __builtin_amdgcn_mfma_f32_16x16x32_bf16(af[mf], bfh[ks][nf], s[mf][nf], 0, 0, 0);
    }
#pragma unroll
    for (int nf = 0; nf < 2; ++nf){
      const float cv = ct[(wn*32 + nf*16 + l16)*17 + k];
#pragma unroll
      for (int mf = 0; mf < 4; ++mf)
#pragma unroll
        for (int reg = 0; reg < 4; ++reg)
          accum[mf][nf][reg] += cv * fastrcp(1.f + __expf(-s[mf][nf][reg]));
    }
  }
#pragma unroll
  for (int mf = 0; mf < 4; ++mf){
    const int r = n0 + wm*64 + mf*16 + quad*4;
#pragma unroll
    for (int nf = 0; nf < 2; ++nf){
      const int col = t0 + wn*32 + nf*16 + l16;
#pragma unroll
      for (int reg = 0; reg < 4; ++reg)
        out[O_APRED + (size_t)(r + reg)*NT + col] = accum[mf][nf][reg];
    }
  }
}

// ---------------- E: a_reconst — 8 rows/block, 512 threads (2 j-rows/thread) ----------------
__global__ __launch_bounds__(512) void k_arec(
    const float* __restrict__ ws_zt, const float* __restrict__ W,
    const float* __restrict__ bias, float* __restrict__ out)
{
  __shared__ float zsh[8 * DZ];
  const int n0 = blockIdx.x * 8, tid = threadIdx.x;
  if (tid < 128)
    ((float4*)zsh)[tid] = ((const float4*)(ws_zt + (size_t)n0 * DZ))[tid];
  __syncthreads();
#pragma unroll
  for (int jo = 0; jo < 2; ++jo){
    const int j = jo*512 + tid;
    const float4* w4 = (const float4*)(W + (size_t)j * DZ);
    const float b = bias[j];
    float acc[8];
#pragma unroll
    for (int r = 0; r < 8; ++r) acc[r] = b;
#pragma unroll
    for (int i = 0; i < 16; ++i){
      float4 wv = w4[i];
#pragma unroll
      for (int r = 0; r < 8; ++r){
        const float* z = &zsh[r*DZ + i*4];
        acc[r] += wv.x*z[0] + wv.y*z[1] + wv.z*z[2] + wv.w*z[3];
      }
    }
#pragma unroll
    for (int r = 0; r < 8; ++r)
      out[O_AREC + (size_t)(n0 + r)*DT + j] = fastrcp(1.f + __expf(-acc[r]));
  }
}

// ---------------- F: fused a_zt + mu_y — azt phase (compensated bf16 MFMA,
//   4-way split-K) reduces into LDS; muy phase (16 waves x 64 j) consumes it
//   directly. Deletes the ws_azt global round-trip + one launch. ----------------
__global__ __launch_bounds__(1024) void k_aztmuy(
    const float* __restrict__ ins, const ushort_t* __restrict__ zhT,
    const ushort_t* __restrict__ zlT, const float* __restrict__ w1T,
    const float* __restrict__ by1, const float* __restrict__ Wy2,
    const float* __restrict__ by2, const float* __restrict__ zi_out,
    float* __restrict__ out)
{
  __shared__ float red[3 * 16 * 64];   // azt split-K partials
  __shared__ float sazt[16 * 64];      // a_zt rows n0..n0+15
  __shared__ float sred[16 * 16];      // muy wave partials
  const int tid = threadIdx.x;
  const int n0 = blockIdx.x * 16;
  const int w = tid >> 6, lane = tid & 63;
  const int kh = w >> 2, wd = w & 3;       // kh: K-quarter (0..3); wd: d-quadrant
  const int l16 = lane & 15, quad = lane >> 4;
  // ---- azt phase (identical math to old k_azt) ----
  {
    const float* aRow = ins + (size_t)(n0 + l16) * NT + kh * 512 + quad * 8;
    const ushort_t* bh = zhT + (size_t)(wd * 16 + l16) * NT + kh * 512 + quad * 8;
    const ushort_t* bl = zlT + (size_t)(wd * 16 + l16) * NT + kh * 512 + quad * 8;
    f32x4 acc = {};
#pragma unroll 4
    for (int kt = 0; kt < 8; ++kt){
#pragma unroll
      for (int ks = 0; ks < 2; ++ks){
        const int ko = kt * 64 + ks * 32;
        float4 a0 = *(const float4*)(aRow + ko);
        float4 a1 = *(const float4*)(aRow + ko + 4);
        uint32 u0 = __float_as_uint(a0.x), u1 = __float_as_uint(a0.y);
        uint32 u2 = __float_as_uint(a0.z), u3 = __float_as_uint(a0.w);
        uint32 u4 = __float_as_uint(a1.x), u5 = __float_as_uint(a1.y);
        uint32 u6 = __float_as_uint(a1.z), u7 = __float_as_uint(a1.w);
        uint4 H, L;
        H.x = (u1 & 0xffff0000u) | (u0 >> 16);
        H.y = (u3 & 0xffff0000u) | (u2 >> 16);
        H.z = (u5 & 0xffff0000u) | (u4 >> 16);
        H.w = (u7 & 0xffff0000u) | (u6 >> 16);
        float l0 = a0.x - __uint_as_float(u0 & 0xffff0000u);
        float l1 = a0.y - __uint_as_float(u1 & 0xffff0000u);
        float l2 = a0.z - __uint_as_float(u2 & 0xffff0000u);
        float l3 = a0.w - __uint_as_float(u3 & 0xffff0000u);
        float l4 = a1.x - __uint_as_float(u4 & 0xffff0000u);
        float l5 = a1.y - __uint_as_float(u5 & 0xffff0000u);
        float l6 = a1.z - __uint_as_float(u6 & 0xffff0000u);
        float l7 = a1.w - __uint_as_float(u7 & 0xffff0000u);
        L.x = pk(l0, l1); L.y = pk(l2, l3); L.z = pk(l4, l5); L.w = pk(l6, l7);
        short8 ah = *(short8*)&H, al = *(short8*)&L;
        short8 bh8 = *(const short8*)(bh + ko);
        short8 bl8 = *(const short8*)(bl + ko);
        acc = __builtin_amdgcn_mfma_f32_16x16x32_bf16(ah, bh8, acc, 0, 0, 0);
        acc = __builtin_amdgcn_mfma_f32_16x16x32_bf16(al, bh8, acc, 0, 0, 0);
        acc = __builtin_amdgcn_mfma_f32_16x16x32_bf16(ah, bl8, acc, 0, 0, 0);
      }
    }
    const int col = wd * 16 + l16;
    if (kh > 0){
#pragma unroll
      for (int reg = 0; reg < 4; ++reg)
        red[(kh-1)*1024 + (quad*4 + reg)*64 + col] = acc[reg];
    }
    __syncthreads();
    if (kh == 0){
#pragma unroll
      for (int reg = 0; reg < 4; ++reg){
        const int idx = (quad*4 + reg)*64 + col;
        sazt[idx] = acc[reg] + red[idx] + red[1024 + idx] + red[2048 + idx];
      }
    }
    __syncthreads();
  }
  // ---- muy phase: 16 waves, each owns 64 consecutive j (j = w*64+lane) ----
  const int jw = w * 64 + lane;
  float rep[16];
#pragma unroll
  for (int n = 0; n < 16; ++n) rep[n] = 0.f;
#pragma unroll 4
  for (int d4 = 0; d4 < 16; ++d4){
    const float* wrow = w1T + (size_t)(d4*4) * KD;
    const float w0 = wrow[jw];
    const float w1 = wrow[KD + jw];
    const float w2 = wrow[2*KD + jw];
    const float w3 = wrow[3*KD + jw];
#pragma unroll
    for (int n = 0; n < 16; ++n){
      float4 av = *(const float4*)&sazt[n*64 + d4*4];
      rep[n] += av.x*w0 + av.y*w1 + av.z*w2 + av.w*w3;
    }
  }
  const float add = by1[jw] + Wy2[jw];
  // zi_all[n, j] = zi_out[(j>>6)*(NI*DZ) + n*DZ + (j&63)]; jw>>6 = w, jw&63 = lane
  const size_t zb = (size_t)w * (NI*DZ) + lane;
#pragma unroll
  for (int n = 0; n < 16; ++n){
    float p = (rep[n] + add) * zi_out[zb + (size_t)(n0 + n) * DZ];
    p = wred64(p);
    if (lane == 0) sred[w*16 + n] = p;
  }
  __syncthreads();
  if (tid < 16){
    float s = by2[0];
#pragma unroll
    for (int ww = 0; ww < 16; ++ww) s += sred[ww*16 + tid];
    out[O_MU_Y + n0 + tid] = s;
    out[O_LV_Y + n0 + tid] = 1.0f;
  }
}

extern "C" void kernel_launch(void* const* d_in, const int* in_sizes, int n_in,
                              void* d_out, int out_size, void* d_ws, size_t ws_size,
                              hipStream_t stream)
{
  (void)in_sizes; (void)n_in; (void)out_size; (void)ws_size;
  const float* ins   = (const float*)d_in[0];
  const float* treat = (const float*)d_in[1];
  const float* Wmzt  = (const float*)d_in[2];
  const float* bmzt  = (const float*)d_in[3];
  const float* Wlzt  = (const float*)d_in[4];
  const float* blzt  = (const float*)d_in[5];
  const float* Warec = (const float*)d_in[6];
  const float* barec = (const float*)d_in[7];
  const float* Wmzi  = (const float*)d_in[8];
  const float* bmzi  = (const float*)d_in[9];
  const float* Wlzi  = (const float*)d_in[10];
  const float* blzi  = (const float*)d_in[11];
  const float* mu_p  = (const float*)d_in[12];
  const float* lv_p  = (const float*)d_in[13];
  const float* Wy1   = (const float*)d_in[14];
  const float* by1   = (const float*)d_in[15];
  const float* Wy2   = (const float*)d_in[16];
  const float* by2   = (const float*)d_in[17];
  float* out = (float*)d_out;
  float* wsf = (float*)d_ws;
  ushort_t* wsu = (ushort_t*)(wsf + WSF_END);

  float* ws_zt  = wsf + WSF_ZT;
  float* ws_c   = wsf + WSF_C;
  float* ws_cT  = wsf + WSF_CT;
  ushort_t* ztb  = wsu + WSU_ZTB;
  ushort_t* Bc   = wsu + WSU_BC;
  ushort_t* zib  = wsu + WSU_ZIB;
  ushort_t* insb = wsu + WSU_INSB;
  ushort_t* zhT  = wsu + WSU_ZHT;
  ushort_t* zlT  = wsu + WSU_ZLT;
  ushort_t* wbh  = wsu + WSU_WBH;
  ushort_t* wbl  = wsu + WSU_WBL;
  float* w1T     = (float*)(wsu + WSU_END);   // [DZ*KD] fp32 (4B-aligned)

  k_prep0   <<<2132, 256, 0, stream>>>(ins, Wy1, Wmzt, Wlzt, mu_p, lv_p, insb, w1T, wbh, wbl, out);
  k_encode_t<<<NT/16, 512, 0, stream>>>(treat, wbh, wbl, bmzt, blzt, mu_p, out, ws_zt, ztb, zhT, zlT, ws_c, ws_cT);
  k_prep1   <<<2048, 256, 0, stream>>>(Wmzi, Wlzi, ws_cT, Bc);
  k_encode_i<<<dim3(16, 32), 256, 0, stream>>>(insb, Bc, bmzi, blzi, out, zib);
  k_decoder <<<dim3(32, 32), 256, 0, stream>>>(ztb, zib, ws_c, out);
  k_arec    <<<NT/8, 512, 0, stream>>>(ws_zt, Warec, barec, out);
  k_aztmuy  <<<NI/16, 1024, 0, stream>>>(ins, zhT, zlT, w1T, by1, Wy2, by2, out + O_ZI, out);
}